// Round 5
// baseline (373.590 us; speedup 1.0000x reference)
//
#include <hip/hip_runtime.h>
#include <hip/hip_fp16.h>

#define N_NODES 50000
#define N_EDGES 800000
#define IN_DIM  128
#define HID     64
#define HID2    32
#define HEADS   4
#define LATENT  32
#define NEG_SLOPE 0.2f

// ---------------- workspace layout (float offsets) ----------------
#define OFF_XH1H  ((size_t)0)            //  6,400,000 (half storage)
#define OFF_XH2H  ((size_t)0)            //  3,200,000 (overlay, xh1 dead)
#define OFF_AGG2  ((size_t)6400000)      //  1,600,000
#define OFF_ALS2  ((size_t)8000000)      //    200,000
#define OFF_ALD2  ((size_t)8200000)      //    200,000
#define OFF_AGG1  ((size_t)8400000)      //  3,200,000
#define OFF_ALS1  ((size_t)11600000)     //    200,000
#define OFF_ALD1  ((size_t)11800000)     //    200,000
// CSR (ints in float slots)
#define OFF_DEG   ((size_t)12000000)     //     50,000 (reused as scatter cursor)
#define OFF_ROW   ((size_t)12050000)     //     50,001
#define OFF_BSUM  ((size_t)12100004)     //        256
#define OFF_ESRC  ((size_t)12100260)     //    800,000
// total 12,900,260 floats = 51.6 MB

#define NB_SCAN ((N_NODES + 255) / 256)  // 196

__device__ __forceinline__ float lrelu(float v) {
    return v > 0.f ? v : NEG_SLOPE * v;
}

// ---------------- K1: xh1h = half(x @ W1) ; als1/ald1 (fp32) ----------------
// 16 nodes/block, 256 threads (thread = out col). Inner: 16 ds_read_b128 + 64 FMA / 4k.
#define NPB1 16
__global__ void k_gemm1(const float* __restrict__ x, const float* __restrict__ W1,
                        const float* __restrict__ as1, const float* __restrict__ ad1,
                        __half* __restrict__ xh1, float* __restrict__ als,
                        float* __restrict__ ald) {
    __shared__ float xs[NPB1][IN_DIM];   // 8 KB, one contiguous chunk of x
    const int tid = threadIdx.x;              // 256
    const int n0  = blockIdx.x * NPB1;
    {
        const float4* src = (const float4*)(x + (size_t)n0 * IN_DIM);
        float4* dstp = (float4*)xs;
#pragma unroll
        for (int i = 0; i < (NPB1 * IN_DIM / 4) / 256; i++)
            dstp[tid + i * 256] = src[tid + i * 256];
    }
    __syncthreads();
    float acc[NPB1];
#pragma unroll
    for (int i = 0; i < NPB1; i++) acc[i] = 0.f;
    for (int k = 0; k < IN_DIM; k += 4) {
        const float w0 = W1[(k + 0) * (HEADS * HID) + tid];
        const float w1 = W1[(k + 1) * (HEADS * HID) + tid];
        const float w2 = W1[(k + 2) * (HEADS * HID) + tid];
        const float w3 = W1[(k + 3) * (HEADS * HID) + tid];
#pragma unroll
        for (int i = 0; i < NPB1; i++) {
            const float4 xv = *(const float4*)&xs[i][k];
            float a = acc[i];
            a = fmaf(xv.x, w0, a);
            a = fmaf(xv.y, w1, a);
            a = fmaf(xv.z, w2, a);
            a = fmaf(xv.w, w3, a);
            acc[i] = a;
        }
    }
    const int h = tid >> 6, c = tid & 63;     // wave == one head
    const float asv = as1[h * HID + c], adv = ad1[h * HID + c];
#pragma unroll
    for (int i = 0; i < NPB1; i++) {
        const int n = n0 + i;
        xh1[(size_t)n * (HEADS * HID) + tid] = __float2half(acc[i]);
        float ps = acc[i] * asv, pd = acc[i] * adv;
        for (int off = 32; off; off >>= 1) {
            ps += __shfl_down(ps, off);
            pd += __shfl_down(pd, off);
        }
        if (c == 0) { als[n * HEADS + h] = ps; ald[n * HEADS + h] = pd; }
    }
}

// ---------------- CSR build ----------------
__global__ void k_hist(const int* __restrict__ ei, int* __restrict__ deg) {
    const int e = blockIdx.x * blockDim.x + threadIdx.x;
    if (e >= N_EDGES) return;
    atomicAdd(&deg[ei[N_EDGES + e]], 1);
}

__global__ void k_scan_part(const int* __restrict__ deg, int* __restrict__ row,
                            int* __restrict__ bsum) {
    __shared__ int sm[256];
    const int tid = threadIdx.x;
    const int i = blockIdx.x * 256 + tid;
    const int v = (i < N_NODES) ? deg[i] : 0;
    sm[tid] = v;
    __syncthreads();
    for (int off = 1; off < 256; off <<= 1) {
        int t = (tid >= off) ? sm[tid - off] : 0;
        __syncthreads();
        sm[tid] += t;
        __syncthreads();
    }
    if (i < N_NODES) row[i] = sm[tid] - v;      // within-block exclusive
    if (tid == 255) bsum[blockIdx.x] = sm[255];
}

__global__ void k_scan_block(int* __restrict__ bsum) {
    __shared__ int sm[256];
    const int tid = threadIdx.x;
    const int v = (tid < NB_SCAN) ? bsum[tid] : 0;
    sm[tid] = v;
    __syncthreads();
    for (int off = 1; off < 256; off <<= 1) {
        int t = (tid >= off) ? sm[tid - off] : 0;
        __syncthreads();
        sm[tid] += t;
        __syncthreads();
    }
    if (tid < NB_SCAN) bsum[tid] = sm[tid] - v; // exclusive block offsets
}

__global__ void k_scan_add(int* __restrict__ row, const int* __restrict__ bsum,
                           int* __restrict__ cur) {
    const int i = blockIdx.x * 256 + threadIdx.x;
    if (i == 0) row[N_NODES] = N_EDGES;
    if (i >= N_NODES) return;
    const int r = row[i] + bsum[blockIdx.x];
    row[i] = r;
    cur[i] = r;
}

__global__ void k_scatter(const int* __restrict__ ei, int* __restrict__ cur,
                          int* __restrict__ esrc) {
    const int e = blockIdx.x * blockDim.x + threadIdx.x;
    if (e >= N_EDGES) return;
    const int s = ei[e], d = ei[N_EDGES + e];
    const int pos = atomicAdd(&cur[d], 1);
    esrc[pos] = s;
}

// ---------------- K3: layer-1 aggregation. Wave per node, all-shuffle ----------------
__global__ void k_agg1_h(const int* __restrict__ row, const int* __restrict__ esrc,
                         const float* __restrict__ als, const float* __restrict__ ald,
                         const __half* __restrict__ xh1, float* __restrict__ agg1) {
    const int d = blockIdx.x * 4 + (threadIdx.x >> 6);
    const int lane = threadIdx.x & 63;
    if (d >= N_NODES) return;
    const int hq = lane >> 4;       // head this lane accumulates
    const int he = lane & 3;        // head this lane exponentiates
    const float adh = ald[d * 4 + he];
    const int start = row[d];
    const int total = row[d + 1] - start + 1;   // + self loop
    float acc0 = 0.f, acc1 = 0.f, acc2 = 0.f, acc3 = 0.f;
    float denp = 0.f;
    for (int t0 = 0; t0 < total; t0 += 16) {
        int m = total - t0; if (m > 16) m = 16;
        const int slot = lane >> 2;
        float ev = 0.f; int s = d;
        if (slot < m) {
            const int t = t0 + slot;
            if (t > 0) s = esrc[start + t - 1];
            ev = expf(lrelu(als[s * 4 + he] + adh));
        }
        denp += ev;
        for (int j = 0; j < m; j++) {
            const float cf = __shfl(ev, j * 4 + hq);
            const int sj   = __shfl(s, j * 4);
            const float2 raw = *(const float2*)((const char*)xh1 +
                                 ((size_t)sj << 9) + (lane << 3));
            const __half2 h01 = *(const __half2*)&raw.x;
            const __half2 h23 = *(const __half2*)&raw.y;
            const float2 x01 = __half22float2(h01);
            const float2 x23 = __half22float2(h23);
            acc0 += cf * x01.x; acc1 += cf * x01.y;
            acc2 += cf * x23.x; acc3 += cf * x23.y;
        }
    }
    denp += __shfl_xor(denp, 4);
    denp += __shfl_xor(denp, 8);
    denp += __shfl_xor(denp, 16);
    denp += __shfl_xor(denp, 32);
    const float deninv = 1.f / __shfl(denp, hq);
    acc0 *= deninv; acc1 *= deninv; acc2 *= deninv; acc3 *= deninv;
    acc0 += __shfl_xor(acc0, 16); acc0 += __shfl_xor(acc0, 32);
    acc1 += __shfl_xor(acc1, 16); acc1 += __shfl_xor(acc1, 32);
    acc2 += __shfl_xor(acc2, 16); acc2 += __shfl_xor(acc2, 32);
    acc3 += __shfl_xor(acc3, 16); acc3 += __shfl_xor(acc3, 32);
    if (lane < 16) {
        float4 st = { 0.25f * acc0, 0.25f * acc1, 0.25f * acc2, 0.25f * acc3 };
        *(float4*)(agg1 + (size_t)d * HID + lane * 4) = st;
    }
}

// ---------------- K5: h1 = relu(agg1+b1); xh2h = half(h1 @ W2) ; als2/ald2 ----------------
// 16 nodes/block, 128 threads (thread = out col). Inner: 16 ds_read_b128 + 64 FMA / 4k.
#define NPB2 16
__global__ void k_gemm2(const float* __restrict__ agg1, const float* __restrict__ b1,
                        const float* __restrict__ W2, const float* __restrict__ as2,
                        const float* __restrict__ ad2, __half* __restrict__ xh2,
                        float* __restrict__ als, float* __restrict__ ald) {
    __shared__ float hs[NPB2][HID];      // 4 KB, contiguous chunk of agg1
    const int tid = threadIdx.x;              // 128
    const int n0  = blockIdx.x * NPB2;
    {
        const float4* src = (const float4*)(agg1 + (size_t)n0 * HID);
        float4* dstp = (float4*)hs;
#pragma unroll
        for (int i = 0; i < (NPB2 * HID / 4) / 128; i++) {
            const int idx = tid + i * 128;
            float4 v = src[idx];
            const int cb = (idx * 4) & (HID - 1);
            v.x += b1[cb + 0]; v.y += b1[cb + 1];
            v.z += b1[cb + 2]; v.w += b1[cb + 3];
            v.x = v.x > 0.f ? v.x : 0.f;
            v.y = v.y > 0.f ? v.y : 0.f;
            v.z = v.z > 0.f ? v.z : 0.f;
            v.w = v.w > 0.f ? v.w : 0.f;
            dstp[idx] = v;
        }
    }
    __syncthreads();
    float acc[NPB2];
#pragma unroll
    for (int i = 0; i < NPB2; i++) acc[i] = 0.f;
    for (int k = 0; k < HID; k += 4) {
        const float w0 = W2[(k + 0) * (HEADS * HID2) + tid];
        const float w1 = W2[(k + 1) * (HEADS * HID2) + tid];
        const float w2 = W2[(k + 2) * (HEADS * HID2) + tid];
        const float w3 = W2[(k + 3) * (HEADS * HID2) + tid];
#pragma unroll
        for (int i = 0; i < NPB2; i++) {
            const float4 xv = *(const float4*)&hs[i][k];
            float a = acc[i];
            a = fmaf(xv.x, w0, a);
            a = fmaf(xv.y, w1, a);
            a = fmaf(xv.z, w2, a);
            a = fmaf(xv.w, w3, a);
            acc[i] = a;
        }
    }
    const int h = tid >> 5, c = tid & 31;     // 32-lane group == one head
    const float asv = as2[h * HID2 + c], adv = ad2[h * HID2 + c];
#pragma unroll
    for (int i = 0; i < NPB2; i++) {
        const int n = n0 + i;
        xh2[(size_t)n * (HEADS * HID2) + tid] = __float2half(acc[i]);
        float ps = acc[i] * asv, pd = acc[i] * adv;
        for (int off = 16; off; off >>= 1) {
            ps += __shfl_down(ps, off, 32);
            pd += __shfl_down(pd, off, 32);
        }
        if (c == 0) { als[n * HEADS + h] = ps; ald[n * HEADS + h] = pd; }
    }
}

// ---------------- K7: layer-2 aggregation. Wave per node, all-shuffle ----------------
__global__ void k_agg2_h(const int* __restrict__ row, const int* __restrict__ esrc,
                         const float* __restrict__ als, const float* __restrict__ ald,
                         const __half* __restrict__ xh2, float* __restrict__ agg2) {
    const int d = blockIdx.x * 4 + (threadIdx.x >> 6);
    const int lane = threadIdx.x & 63;
    if (d >= N_NODES) return;
    const int hq = lane >> 4;
    const int he = lane & 3;
    const float adh = ald[d * 4 + he];
    const int start = row[d];
    const int total = row[d + 1] - start + 1;   // + self loop
    float acc0 = 0.f, acc1 = 0.f;
    float denp = 0.f;
    for (int t0 = 0; t0 < total; t0 += 16) {
        int m = total - t0; if (m > 16) m = 16;
        const int slot = lane >> 2;
        float ev = 0.f; int s = d;
        if (slot < m) {
            const int t = t0 + slot;
            if (t > 0) s = esrc[start + t - 1];
            ev = expf(lrelu(als[s * 4 + he] + adh));
        }
        denp += ev;
        for (int j = 0; j < m; j++) {
            const float cf = __shfl(ev, j * 4 + hq);
            const int sj   = __shfl(s, j * 4);
            const __half2 hv = *(const __half2*)((const char*)xh2 +
                                ((size_t)sj << 8) + (lane << 2));
            const float2 xv = __half22float2(hv);
            acc0 += cf * xv.x; acc1 += cf * xv.y;
        }
    }
    denp += __shfl_xor(denp, 4);
    denp += __shfl_xor(denp, 8);
    denp += __shfl_xor(denp, 16);
    denp += __shfl_xor(denp, 32);
    const float deninv = 1.f / __shfl(denp, hq);
    acc0 *= deninv; acc1 *= deninv;
    acc0 += __shfl_xor(acc0, 16); acc0 += __shfl_xor(acc0, 32);
    acc1 += __shfl_xor(acc1, 16); acc1 += __shfl_xor(acc1, 32);
    if (lane < 16) {
        float2 st = { 0.25f * acc0, 0.25f * acc1 };
        *(float2*)(agg2 + (size_t)d * HID2 + lane * 2) = st;
    }
}

// ---------------- K8: final projections ----------------
#define NPB3 4
__global__ void k_final(const float* __restrict__ agg2, const float* __restrict__ b2,
                        const float* __restrict__ Wmu, const float* __restrict__ bmu,
                        const float* __restrict__ Wlv, const float* __restrict__ blv,
                        float* __restrict__ out) {
    __shared__ float hs[NPB3][HID2];
    const int tid = threadIdx.x;              // 256
    const int n0  = blockIdx.x * NPB3;
    if (tid < NPB3 * HID2) {
        int ni = tid >> 5, ci = tid & 31;
        float v = agg2[(size_t)(n0 + ni) * HID2 + ci] + b2[ci];
        hs[ni][ci] = v > 0.f ? v : 0.f;
    }
    __syncthreads();
    const int ni = tid >> 6;                  // 4 nodes per block
    const int which = (tid >> 5) & 1;         // 0 = mu, 1 = logvar
    const int l = tid & 31;
    const float* W = which ? Wlv : Wmu;
    const float* b = which ? blv : bmu;
    float acc = b[l];
#pragma unroll
    for (int c = 0; c < HID2; c++) acc += hs[ni][c] * W[c * LATENT + l];
    const int n = n0 + ni;
    out[(size_t)which * N_NODES * LATENT + (size_t)n * LATENT + l] = acc;
}

extern "C" void kernel_launch(void* const* d_in, const int* in_sizes, int n_in,
                              void* d_out, int out_size, void* d_ws, size_t ws_size,
                              hipStream_t stream) {
    const float* x    = (const float*)d_in[0];
    const int*   ei   = (const int*)d_in[1];
    const float* W1   = (const float*)d_in[2];
    const float* as1  = (const float*)d_in[3];
    const float* ad1  = (const float*)d_in[4];
    const float* b1   = (const float*)d_in[5];
    const float* W2   = (const float*)d_in[6];
    const float* as2  = (const float*)d_in[7];
    const float* ad2  = (const float*)d_in[8];
    const float* b2   = (const float*)d_in[9];
    const float* Wmu  = (const float*)d_in[10];
    const float* bmu  = (const float*)d_in[11];
    const float* Wlv  = (const float*)d_in[12];
    const float* blv  = (const float*)d_in[13];
    float* out = (float*)d_out;
    float* ws  = (float*)d_ws;

    __half* xh1h = (__half*)(ws + OFF_XH1H);
    __half* xh2h = (__half*)(ws + OFF_XH2H);
    float* als1 = ws + OFF_ALS1;
    float* ald1 = ws + OFF_ALD1;
    float* agg1 = ws + OFF_AGG1;
    float* als2 = ws + OFF_ALS2;
    float* ald2 = ws + OFF_ALD2;
    float* agg2 = ws + OFF_AGG2;
    int* deg  = (int*)(ws + OFF_DEG);   // also scatter cursor
    int* rowp = (int*)(ws + OFF_ROW);
    int* bsum = (int*)(ws + OFF_BSUM);
    int* esrc = (int*)(ws + OFF_ESRC);

    hipMemsetAsync(deg, 0, N_NODES * sizeof(int), stream);

    k_gemm1<<<N_NODES / NPB1, 256, 0, stream>>>(x, W1, as1, ad1, xh1h, als1, ald1);

    // CSR build (dst-major)
    k_hist<<<(N_EDGES + 255) / 256, 256, 0, stream>>>(ei, deg);
    k_scan_part<<<NB_SCAN, 256, 0, stream>>>(deg, rowp, bsum);
    k_scan_block<<<1, 256, 0, stream>>>(bsum);
    k_scan_add<<<NB_SCAN, 256, 0, stream>>>(rowp, bsum, deg /*cursor*/);
    k_scatter<<<(N_EDGES + 255) / 256, 256, 0, stream>>>(ei, deg /*cursor*/, esrc);

    k_agg1_h<<<(N_NODES + 3) / 4, 256, 0, stream>>>(rowp, esrc, als1, ald1, xh1h, agg1);

    k_gemm2<<<N_NODES / NPB2, 128, 0, stream>>>(agg1, b1, W2, as2, ad2, xh2h, als2, ald2);

    k_agg2_h<<<(N_NODES + 3) / 4, 256, 0, stream>>>(rowp, esrc, als2, ald2, xh2h, agg2);

    k_final<<<N_NODES / NPB3, 256, 0, stream>>>(agg2, b2, Wmu, bmu, Wlv, blv, out);
}

// Round 6
// 320.138 us; speedup vs baseline: 1.1670x; 1.1670x over previous
//
#include <hip/hip_runtime.h>
#include <hip/hip_fp16.h>

#define N_NODES 50000
#define N_EDGES 800000
#define IN_DIM  128
#define HID     64
#define HID2    32
#define HEADS   4
#define LATENT  32
#define NEG_SLOPE 0.2f

typedef _Float16 half8v __attribute__((ext_vector_type(8)));
typedef _Float16 half4v __attribute__((ext_vector_type(4)));
typedef float    float4v __attribute__((ext_vector_type(4)));

// ---------------- workspace layout (float offsets) ----------------
#define OFF_XH1H  ((size_t)0)            //  6,400,000 (half storage)
#define OFF_XH2H  ((size_t)0)            //  3,200,000 (overlay, xh1 dead)
#define OFF_AGG2  ((size_t)6400000)      //  1,600,000
#define OFF_ALS2  ((size_t)8000000)      //    200,000
#define OFF_ALD2  ((size_t)8200000)      //    200,000
#define OFF_AGG1  ((size_t)8400000)      //  3,200,000
#define OFF_ALS1  ((size_t)11600000)     //    200,000
#define OFF_ALD1  ((size_t)11800000)     //    200,000
// CSR (ints in float slots)
#define OFF_DEG   ((size_t)12000000)     //     50,000 (reused as scatter cursor)
#define OFF_ROW   ((size_t)12050000)     //     50,001
#define OFF_BSUM  ((size_t)12100004)     //        256
#define OFF_ESRC  ((size_t)12100260)     //    800,000
#define OFF_W1TH  ((size_t)12900260)     //     16,384 float slots (32768 halves)
// total ~12,916,644 floats = 51.7 MB

#define NB_SCAN ((N_NODES + 255) / 256)  // 196

__device__ __forceinline__ float lrelu(float v) {
    return v > 0.f ? v : NEG_SLOPE * v;
}

// ---------------- K0: W1 fp32 [128][256] -> fp16 transposed [256][128] ----------------
__global__ void k_cvt_w(const float* __restrict__ W1, __half* __restrict__ w1t) {
    const int t = blockIdx.x * 256 + threadIdx.x;   // 32768 elems
    const int k = t >> 8, n = t & 255;
    w1t[n * IN_DIM + k] = __float2half(W1[t]);
}

// ---------------- K1: xh1h = half(x @ W1) via MFMA 16x16x32 f16 ----------------
// Block: 256 thr / 4 waves; tile 64 nodes x 64 cols; K=128 in one LDS stage.
__global__ void k_gemm1_mfma(const float* __restrict__ x, const __half* __restrict__ w1t,
                             __half* __restrict__ xh1) {
    __shared__ _Float16 xsh[64][136];   // padded: 272B row stride (bank-spread)
    __shared__ _Float16 wsh[64][136];
    const int tid = threadIdx.x;
    const int mb = blockIdx.x >> 2;     // 782 M-blocks of 64 nodes
    const int n0 = (blockIdx.x & 3) * 64;
    const int m0 = mb * 64;
    // stage x tile (fp32 -> fp16), 2048 float4 / 256 thr
#pragma unroll
    for (int i = 0; i < 8; i++) {
        const int f = tid + i * 256;
        const int r = f >> 5;              // 32 float4 per 128-col row
        const int k = (f & 31) * 4;
        const int gr = (m0 + r < N_NODES) ? (m0 + r) : (N_NODES - 1);
        const float4 xv = *(const float4*)(x + (size_t)gr * IN_DIM + k);
        half4v hv = { (_Float16)xv.x, (_Float16)xv.y, (_Float16)xv.z, (_Float16)xv.w };
        *(half4v*)&xsh[r][k] = hv;
    }
    // stage W1^T tile (fp16 copy), 1024 x 16B / 256 thr
#pragma unroll
    for (int i = 0; i < 4; i++) {
        const int u = tid + i * 256;
        const int r = u >> 4;              // 16 half8 per 128-col row
        const int k = (u & 15) * 8;
        *(half8v*)&wsh[r][k] = *(const half8v*)(w1t + (size_t)(n0 + r) * IN_DIM + k);
    }
    __syncthreads();
    const int w = tid >> 6, l = tid & 63;
    const int lr = l & 15;
    const int lk = (l >> 4) * 8;
    float4v acc0 = {0.f,0.f,0.f,0.f}, acc1 = {0.f,0.f,0.f,0.f};
    float4v acc2 = {0.f,0.f,0.f,0.f}, acc3 = {0.f,0.f,0.f,0.f};
#pragma unroll
    for (int k0 = 0; k0 < IN_DIM; k0 += 32) {
        const half8v a  = *(const half8v*)&xsh[w * 16 + lr][k0 + lk];
        const half8v b0 = *(const half8v*)&wsh[ 0 + lr][k0 + lk];
        const half8v b1 = *(const half8v*)&wsh[16 + lr][k0 + lk];
        const half8v b2 = *(const half8v*)&wsh[32 + lr][k0 + lk];
        const half8v b3 = *(const half8v*)&wsh[48 + lr][k0 + lk];
        acc0 = __builtin_amdgcn_mfma_f32_16x16x32_f16(a, b0, acc0, 0, 0, 0);
        acc1 = __builtin_amdgcn_mfma_f32_16x16x32_f16(a, b1, acc1, 0, 0, 0);
        acc2 = __builtin_amdgcn_mfma_f32_16x16x32_f16(a, b2, acc2, 0, 0, 0);
        acc3 = __builtin_amdgcn_mfma_f32_16x16x32_f16(a, b3, acc3, 0, 0, 0);
    }
    // C/D layout: col = l&15, row = (l>>4)*4 + reg
    const int rbase = m0 + w * 16 + (l >> 4) * 4;
    const int cbase = n0 + lr;
#pragma unroll
    for (int r = 0; r < 4; r++) {
        const int node = rbase + r;
        if (node < N_NODES) {
            __half* p = xh1 + (size_t)node * (HEADS * HID) + cbase;
            p[0]  = __float2half(acc0[r]);
            p[16] = __float2half(acc1[r]);
            p[32] = __float2half(acc2[r]);
            p[48] = __float2half(acc3[r]);
        }
    }
}

// ---------------- K1b: als1/ald1 from xh1h (fp32 math) ----------------
__global__ void k_attn1(const __half* __restrict__ xh1, const float* __restrict__ as1,
                        const float* __restrict__ ad1, float* __restrict__ als,
                        float* __restrict__ ald) {
    const int n = blockIdx.x * 4 + (threadIdx.x >> 6);
    const int l = threadIdx.x & 63;
    if (n >= N_NODES) return;
    // lane l covers cols 4l..4l+3; head = l>>4
    const float4 av = *(const float4*)(as1 + l * 4);
    const float4 dv = *(const float4*)(ad1 + l * 4);
    const float2 raw = *(const float2*)((const char*)xh1 + (size_t)n * 512 + l * 8);
    const __half2 h01 = *(const __half2*)&raw.x;
    const __half2 h23 = *(const __half2*)&raw.y;
    const float2 x01 = __half22float2(h01);
    const float2 x23 = __half22float2(h23);
    float ps = x01.x * av.x + x01.y * av.y + x23.x * av.z + x23.y * av.w;
    float pd = x01.x * dv.x + x01.y * dv.y + x23.x * dv.z + x23.y * dv.w;
    ps += __shfl_xor(ps, 1); pd += __shfl_xor(pd, 1);
    ps += __shfl_xor(ps, 2); pd += __shfl_xor(pd, 2);
    ps += __shfl_xor(ps, 4); pd += __shfl_xor(pd, 4);
    ps += __shfl_xor(ps, 8); pd += __shfl_xor(pd, 8);
    if ((l & 15) == 0) {
        als[n * HEADS + (l >> 4)] = ps;
        ald[n * HEADS + (l >> 4)] = pd;
    }
}

// ---------------- CSR build ----------------
__global__ void k_hist(const int* __restrict__ ei, int* __restrict__ deg) {
    const int e = blockIdx.x * blockDim.x + threadIdx.x;
    if (e >= N_EDGES) return;
    atomicAdd(&deg[ei[N_EDGES + e]], 1);
}

__global__ void k_scan_part(const int* __restrict__ deg, int* __restrict__ row,
                            int* __restrict__ bsum) {
    __shared__ int sm[256];
    const int tid = threadIdx.x;
    const int i = blockIdx.x * 256 + tid;
    const int v = (i < N_NODES) ? deg[i] : 0;
    sm[tid] = v;
    __syncthreads();
    for (int off = 1; off < 256; off <<= 1) {
        int t = (tid >= off) ? sm[tid - off] : 0;
        __syncthreads();
        sm[tid] += t;
        __syncthreads();
    }
    if (i < N_NODES) row[i] = sm[tid] - v;      // within-block exclusive
    if (tid == 255) bsum[blockIdx.x] = sm[255];
}

__global__ void k_scan_block(int* __restrict__ bsum) {
    __shared__ int sm[256];
    const int tid = threadIdx.x;
    const int v = (tid < NB_SCAN) ? bsum[tid] : 0;
    sm[tid] = v;
    __syncthreads();
    for (int off = 1; off < 256; off <<= 1) {
        int t = (tid >= off) ? sm[tid - off] : 0;
        __syncthreads();
        sm[tid] += t;
        __syncthreads();
    }
    if (tid < NB_SCAN) bsum[tid] = sm[tid] - v; // exclusive block offsets
}

__global__ void k_scan_add(int* __restrict__ row, const int* __restrict__ bsum,
                           int* __restrict__ cur) {
    const int i = blockIdx.x * 256 + threadIdx.x;
    if (i == 0) row[N_NODES] = N_EDGES;
    if (i >= N_NODES) return;
    const int r = row[i] + bsum[blockIdx.x];
    row[i] = r;
    cur[i] = r;
}

__global__ void k_scatter(const int* __restrict__ ei, int* __restrict__ cur,
                          int* __restrict__ esrc) {
    const int e = blockIdx.x * blockDim.x + threadIdx.x;
    if (e >= N_EDGES) return;
    const int s = ei[e], d = ei[N_EDGES + e];
    const int pos = atomicAdd(&cur[d], 1);
    esrc[pos] = s;
}

// ---------------- K3: layer-1 aggregation. Wave per node, all-shuffle ----------------
__global__ void k_agg1_h(const int* __restrict__ row, const int* __restrict__ esrc,
                         const float* __restrict__ als, const float* __restrict__ ald,
                         const __half* __restrict__ xh1, float* __restrict__ agg1) {
    const int d = blockIdx.x * 4 + (threadIdx.x >> 6);
    const int lane = threadIdx.x & 63;
    if (d >= N_NODES) return;
    const int hq = lane >> 4;       // head this lane accumulates
    const int he = lane & 3;        // head this lane exponentiates
    const float adh = ald[d * 4 + he];
    const int start = row[d];
    const int total = row[d + 1] - start + 1;   // + self loop
    float acc0 = 0.f, acc1 = 0.f, acc2 = 0.f, acc3 = 0.f;
    float denp = 0.f;
    for (int t0 = 0; t0 < total; t0 += 16) {
        int m = total - t0; if (m > 16) m = 16;
        const int slot = lane >> 2;
        float ev = 0.f; int s = d;
        if (slot < m) {
            const int t = t0 + slot;
            if (t > 0) s = esrc[start + t - 1];
            ev = expf(lrelu(als[s * 4 + he] + adh));
        }
        denp += ev;
        for (int j = 0; j < m; j++) {
            const float cf = __shfl(ev, j * 4 + hq);
            const int sj   = __shfl(s, j * 4);
            const float2 raw = *(const float2*)((const char*)xh1 +
                                 ((size_t)sj << 9) + (lane << 3));
            const __half2 h01 = *(const __half2*)&raw.x;
            const __half2 h23 = *(const __half2*)&raw.y;
            const float2 x01 = __half22float2(h01);
            const float2 x23 = __half22float2(h23);
            acc0 += cf * x01.x; acc1 += cf * x01.y;
            acc2 += cf * x23.x; acc3 += cf * x23.y;
        }
    }
    denp += __shfl_xor(denp, 4);
    denp += __shfl_xor(denp, 8);
    denp += __shfl_xor(denp, 16);
    denp += __shfl_xor(denp, 32);
    const float deninv = 1.f / __shfl(denp, hq);
    acc0 *= deninv; acc1 *= deninv; acc2 *= deninv; acc3 *= deninv;
    acc0 += __shfl_xor(acc0, 16); acc0 += __shfl_xor(acc0, 32);
    acc1 += __shfl_xor(acc1, 16); acc1 += __shfl_xor(acc1, 32);
    acc2 += __shfl_xor(acc2, 16); acc2 += __shfl_xor(acc2, 32);
    acc3 += __shfl_xor(acc3, 16); acc3 += __shfl_xor(acc3, 32);
    if (lane < 16) {
        float4 st = { 0.25f * acc0, 0.25f * acc1, 0.25f * acc2, 0.25f * acc3 };
        *(float4*)(agg1 + (size_t)d * HID + lane * 4) = st;
    }
}

// ---------------- K5: h1 = relu(agg1+b1); xh2h = half(h1 @ W2) ; als2/ald2 ----------------
#define NPB2 16
__global__ void k_gemm2(const float* __restrict__ agg1, const float* __restrict__ b1,
                        const float* __restrict__ W2, const float* __restrict__ as2,
                        const float* __restrict__ ad2, __half* __restrict__ xh2,
                        float* __restrict__ als, float* __restrict__ ald) {
    __shared__ float hs[NPB2][HID];      // 4 KB, contiguous chunk of agg1
    const int tid = threadIdx.x;              // 128
    const int n0  = blockIdx.x * NPB2;
    {
        const float4* src = (const float4*)(agg1 + (size_t)n0 * HID);
        float4* dstp = (float4*)hs;
#pragma unroll
        for (int i = 0; i < (NPB2 * HID / 4) / 128; i++) {
            const int idx = tid + i * 128;
            float4 v = src[idx];
            const int cb = (idx * 4) & (HID - 1);
            v.x += b1[cb + 0]; v.y += b1[cb + 1];
            v.z += b1[cb + 2]; v.w += b1[cb + 3];
            v.x = v.x > 0.f ? v.x : 0.f;
            v.y = v.y > 0.f ? v.y : 0.f;
            v.z = v.z > 0.f ? v.z : 0.f;
            v.w = v.w > 0.f ? v.w : 0.f;
            dstp[idx] = v;
        }
    }
    __syncthreads();
    float acc[NPB2];
#pragma unroll
    for (int i = 0; i < NPB2; i++) acc[i] = 0.f;
    for (int k = 0; k < HID; k += 4) {
        const float w0 = W2[(k + 0) * (HEADS * HID2) + tid];
        const float w1 = W2[(k + 1) * (HEADS * HID2) + tid];
        const float w2 = W2[(k + 2) * (HEADS * HID2) + tid];
        const float w3 = W2[(k + 3) * (HEADS * HID2) + tid];
#pragma unroll
        for (int i = 0; i < NPB2; i++) {
            const float4 xv = *(const float4*)&hs[i][k];
            float a = acc[i];
            a = fmaf(xv.x, w0, a);
            a = fmaf(xv.y, w1, a);
            a = fmaf(xv.z, w2, a);
            a = fmaf(xv.w, w3, a);
            acc[i] = a;
        }
    }
    const int h = tid >> 5, c = tid & 31;     // 32-lane group == one head
    const float asv = as2[h * HID2 + c], adv = ad2[h * HID2 + c];
#pragma unroll
    for (int i = 0; i < NPB2; i++) {
        const int n = n0 + i;
        xh2[(size_t)n * (HEADS * HID2) + tid] = __float2half(acc[i]);
        float ps = acc[i] * asv, pd = acc[i] * adv;
        for (int off = 16; off; off >>= 1) {
            ps += __shfl_down(ps, off, 32);
            pd += __shfl_down(pd, off, 32);
        }
        if (c == 0) { als[n * HEADS + h] = ps; ald[n * HEADS + h] = pd; }
    }
}

// ---------------- K7: layer-2 aggregation. Wave per node, all-shuffle ----------------
__global__ void k_agg2_h(const int* __restrict__ row, const int* __restrict__ esrc,
                         const float* __restrict__ als, const float* __restrict__ ald,
                         const __half* __restrict__ xh2, float* __restrict__ agg2) {
    const int d = blockIdx.x * 4 + (threadIdx.x >> 6);
    const int lane = threadIdx.x & 63;
    if (d >= N_NODES) return;
    const int hq = lane >> 4;
    const int he = lane & 3;
    const float adh = ald[d * 4 + he];
    const int start = row[d];
    const int total = row[d + 1] - start + 1;   // + self loop
    float acc0 = 0.f, acc1 = 0.f;
    float denp = 0.f;
    for (int t0 = 0; t0 < total; t0 += 16) {
        int m = total - t0; if (m > 16) m = 16;
        const int slot = lane >> 2;
        float ev = 0.f; int s = d;
        if (slot < m) {
            const int t = t0 + slot;
            if (t > 0) s = esrc[start + t - 1];
            ev = expf(lrelu(als[s * 4 + he] + adh));
        }
        denp += ev;
        for (int j = 0; j < m; j++) {
            const float cf = __shfl(ev, j * 4 + hq);
            const int sj   = __shfl(s, j * 4);
            const __half2 hv = *(const __half2*)((const char*)xh2 +
                                ((size_t)sj << 8) + (lane << 2));
            const float2 xv = __half22float2(hv);
            acc0 += cf * xv.x; acc1 += cf * xv.y;
        }
    }
    denp += __shfl_xor(denp, 4);
    denp += __shfl_xor(denp, 8);
    denp += __shfl_xor(denp, 16);
    denp += __shfl_xor(denp, 32);
    const float deninv = 1.f / __shfl(denp, hq);
    acc0 *= deninv; acc1 *= deninv;
    acc0 += __shfl_xor(acc0, 16); acc0 += __shfl_xor(acc0, 32);
    acc1 += __shfl_xor(acc1, 16); acc1 += __shfl_xor(acc1, 32);
    if (lane < 16) {
        float2 st = { 0.25f * acc0, 0.25f * acc1 };
        *(float2*)(agg2 + (size_t)d * HID2 + lane * 2) = st;
    }
}

// ---------------- K8: final projections ----------------
#define NPB3 4
__global__ void k_final(const float* __restrict__ agg2, const float* __restrict__ b2,
                        const float* __restrict__ Wmu, const float* __restrict__ bmu,
                        const float* __restrict__ Wlv, const float* __restrict__ blv,
                        float* __restrict__ out) {
    __shared__ float hs[NPB3][HID2];
    const int tid = threadIdx.x;              // 256
    const int n0  = blockIdx.x * NPB3;
    if (tid < NPB3 * HID2) {
        int ni = tid >> 5, ci = tid & 31;
        float v = agg2[(size_t)(n0 + ni) * HID2 + ci] + b2[ci];
        hs[ni][ci] = v > 0.f ? v : 0.f;
    }
    __syncthreads();
    const int ni = tid >> 6;                  // 4 nodes per block
    const int which = (tid >> 5) & 1;         // 0 = mu, 1 = logvar
    const int l = tid & 31;
    const float* W = which ? Wlv : Wmu;
    const float* b = which ? blv : bmu;
    float acc = b[l];
#pragma unroll
    for (int c = 0; c < HID2; c++) acc += hs[ni][c] * W[c * LATENT + l];
    const int n = n0 + ni;
    out[(size_t)which * N_NODES * LATENT + (size_t)n * LATENT + l] = acc;
}

extern "C" void kernel_launch(void* const* d_in, const int* in_sizes, int n_in,
                              void* d_out, int out_size, void* d_ws, size_t ws_size,
                              hipStream_t stream) {
    const float* x    = (const float*)d_in[0];
    const int*   ei   = (const int*)d_in[1];
    const float* W1   = (const float*)d_in[2];
    const float* as1  = (const float*)d_in[3];
    const float* ad1  = (const float*)d_in[4];
    const float* b1   = (const float*)d_in[5];
    const float* W2   = (const float*)d_in[6];
    const float* as2  = (const float*)d_in[7];
    const float* ad2  = (const float*)d_in[8];
    const float* b2   = (const float*)d_in[9];
    const float* Wmu  = (const float*)d_in[10];
    const float* bmu  = (const float*)d_in[11];
    const float* Wlv  = (const float*)d_in[12];
    const float* blv  = (const float*)d_in[13];
    float* out = (float*)d_out;
    float* ws  = (float*)d_ws;

    __half* xh1h = (__half*)(ws + OFF_XH1H);
    __half* xh2h = (__half*)(ws + OFF_XH2H);
    __half* w1th = (__half*)(ws + OFF_W1TH);
    float* als1 = ws + OFF_ALS1;
    float* ald1 = ws + OFF_ALD1;
    float* agg1 = ws + OFF_AGG1;
    float* als2 = ws + OFF_ALS2;
    float* ald2 = ws + OFF_ALD2;
    float* agg2 = ws + OFF_AGG2;
    int* deg  = (int*)(ws + OFF_DEG);   // also scatter cursor
    int* rowp = (int*)(ws + OFF_ROW);
    int* bsum = (int*)(ws + OFF_BSUM);
    int* esrc = (int*)(ws + OFF_ESRC);

    hipMemsetAsync(deg, 0, N_NODES * sizeof(int), stream);

    k_cvt_w<<<(IN_DIM * HEADS * HID) / 256, 256, 0, stream>>>(W1, w1th);
    k_gemm1_mfma<<<782 * 4, 256, 0, stream>>>(x, w1th, xh1h);
    k_attn1<<<(N_NODES + 3) / 4, 256, 0, stream>>>(xh1h, as1, ad1, als1, ald1);

    // CSR build (dst-major)
    k_hist<<<(N_EDGES + 255) / 256, 256, 0, stream>>>(ei, deg);
    k_scan_part<<<NB_SCAN, 256, 0, stream>>>(deg, rowp, bsum);
    k_scan_block<<<1, 256, 0, stream>>>(bsum);
    k_scan_add<<<NB_SCAN, 256, 0, stream>>>(rowp, bsum, deg /*cursor*/);
    k_scatter<<<(N_EDGES + 255) / 256, 256, 0, stream>>>(ei, deg /*cursor*/, esrc);

    k_agg1_h<<<(N_NODES + 3) / 4, 256, 0, stream>>>(rowp, esrc, als1, ald1, xh1h, agg1);

    k_gemm2<<<N_NODES / NPB2, 128, 0, stream>>>(agg1, b1, W2, as2, ad2, xh2h, als2, ald2);

    k_agg2_h<<<(N_NODES + 3) / 4, 256, 0, stream>>>(rowp, esrc, als2, ald2, xh2h, agg2);

    k_final<<<N_NODES / NPB3, 256, 0, stream>>>(agg2, b2, Wmu, bmu, Wlv, blv, out);
}

// Round 7
// 267.687 us; speedup vs baseline: 1.3956x; 1.1959x over previous
//
#include <hip/hip_runtime.h>
#include <hip/hip_fp16.h>

#define N_NODES 50000
#define N_EDGES 800000
#define IN_DIM  128
#define HID     64
#define HID2    32
#define HEADS   4
#define LATENT  32
#define NEG_SLOPE 0.2f

typedef _Float16 half8v __attribute__((ext_vector_type(8)));
typedef _Float16 half4v __attribute__((ext_vector_type(4)));
typedef float    float4v __attribute__((ext_vector_type(4)));

// ---------------- workspace layout (float offsets) ----------------
#define OFF_XH1H  ((size_t)0)            //  6,400,000 (half storage)
#define OFF_XH2H  ((size_t)0)            //  3,200,000 (overlay, xh1 dead)
#define OFF_AGG2  ((size_t)6400000)      //  1,600,000
#define OFF_ALS2  ((size_t)8000000)      //    200,000
#define OFF_ALD2  ((size_t)8200000)      //    200,000
#define OFF_AGG1  ((size_t)8400000)      //  3,200,000
#define OFF_ALS1  ((size_t)11600000)     //    200,000
#define OFF_ALD1  ((size_t)11800000)     //    200,000
// CSR (ints in float slots)
#define OFF_DEG   ((size_t)12000000)     //     50,000 (reused as scatter cursor)
#define OFF_ROW   ((size_t)12050000)     //     50,001
#define OFF_BSUM  ((size_t)12100004)     //        256
#define OFF_ESRC  ((size_t)12100260)     //    800,000
#define OFF_W1TH  ((size_t)12900260)     //     16,384 float slots (32768 halves)
#define OFF_W2TH  ((size_t)12916644)     //      4,096 float slots (8192 halves)
// total ~12,920,740 floats = 51.7 MB

#define NB_SCAN ((N_NODES + 255) / 256)  // 196

__device__ __forceinline__ float lrelu(float v) {
    return v > 0.f ? v : NEG_SLOPE * v;
}

// ---------------- K0: W1 [128][256] -> w1t [256][128] fp16; W2 [64][128] -> w2t [128][64] fp16 ----------------
__global__ void k_cvt_w(const float* __restrict__ W1, const float* __restrict__ W2,
                        __half* __restrict__ w1t, __half* __restrict__ w2t) {
    const int t = blockIdx.x * 256 + threadIdx.x;
    if (t < 32768) {
        const int k = t >> 8, n = t & 255;
        w1t[n * IN_DIM + k] = __float2half(W1[t]);
    } else if (t < 32768 + 8192) {
        const int t2 = t - 32768;
        const int k = t2 >> 7, n = t2 & 127;
        w2t[n * HID + k] = __float2half(W2[t2]);
    }
}

// ---------------- K1: xh1h = half(x @ W1) via MFMA 16x16x32 f16 ----------------
__global__ void k_gemm1_mfma(const float* __restrict__ x, const __half* __restrict__ w1t,
                             __half* __restrict__ xh1) {
    __shared__ _Float16 xsh[64][136];   // padded: 272B row stride (bank-spread)
    __shared__ _Float16 wsh[64][136];
    const int tid = threadIdx.x;
    const int mb = blockIdx.x >> 2;     // 782 M-blocks of 64 nodes
    const int n0 = (blockIdx.x & 3) * 64;
    const int m0 = mb * 64;
#pragma unroll
    for (int i = 0; i < 8; i++) {
        const int f = tid + i * 256;
        const int r = f >> 5;
        const int k = (f & 31) * 4;
        const int gr = (m0 + r < N_NODES) ? (m0 + r) : (N_NODES - 1);
        const float4 xv = *(const float4*)(x + (size_t)gr * IN_DIM + k);
        half4v hv = { (_Float16)xv.x, (_Float16)xv.y, (_Float16)xv.z, (_Float16)xv.w };
        *(half4v*)&xsh[r][k] = hv;
    }
#pragma unroll
    for (int i = 0; i < 4; i++) {
        const int u = tid + i * 256;
        const int r = u >> 4;
        const int k = (u & 15) * 8;
        *(half8v*)&wsh[r][k] = *(const half8v*)(w1t + (size_t)(n0 + r) * IN_DIM + k);
    }
    __syncthreads();
    const int w = tid >> 6, l = tid & 63;
    const int lr = l & 15;
    const int lk = (l >> 4) * 8;
    float4v acc0 = {0.f,0.f,0.f,0.f}, acc1 = {0.f,0.f,0.f,0.f};
    float4v acc2 = {0.f,0.f,0.f,0.f}, acc3 = {0.f,0.f,0.f,0.f};
#pragma unroll
    for (int k0 = 0; k0 < IN_DIM; k0 += 32) {
        const half8v a  = *(const half8v*)&xsh[w * 16 + lr][k0 + lk];
        const half8v b0 = *(const half8v*)&wsh[ 0 + lr][k0 + lk];
        const half8v b1 = *(const half8v*)&wsh[16 + lr][k0 + lk];
        const half8v b2 = *(const half8v*)&wsh[32 + lr][k0 + lk];
        const half8v b3 = *(const half8v*)&wsh[48 + lr][k0 + lk];
        acc0 = __builtin_amdgcn_mfma_f32_16x16x32_f16(a, b0, acc0, 0, 0, 0);
        acc1 = __builtin_amdgcn_mfma_f32_16x16x32_f16(a, b1, acc1, 0, 0, 0);
        acc2 = __builtin_amdgcn_mfma_f32_16x16x32_f16(a, b2, acc2, 0, 0, 0);
        acc3 = __builtin_amdgcn_mfma_f32_16x16x32_f16(a, b3, acc3, 0, 0, 0);
    }
    const int rbase = m0 + w * 16 + (l >> 4) * 4;
    const int cbase = n0 + lr;
#pragma unroll
    for (int r = 0; r < 4; r++) {
        const int node = rbase + r;
        if (node < N_NODES) {
            __half* p = xh1 + (size_t)node * (HEADS * HID) + cbase;
            p[0]  = __float2half(acc0[r]);
            p[16] = __float2half(acc1[r]);
            p[32] = __float2half(acc2[r]);
            p[48] = __float2half(acc3[r]);
        }
    }
}

// ---------------- K1b: als1/ald1 from xh1h ----------------
__global__ void k_attn1(const __half* __restrict__ xh1, const float* __restrict__ as1,
                        const float* __restrict__ ad1, float* __restrict__ als,
                        float* __restrict__ ald) {
    const int n = blockIdx.x * 4 + (threadIdx.x >> 6);
    const int l = threadIdx.x & 63;
    if (n >= N_NODES) return;
    const float4 av = *(const float4*)(as1 + l * 4);
    const float4 dv = *(const float4*)(ad1 + l * 4);
    const float2 raw = *(const float2*)((const char*)xh1 + (size_t)n * 512 + l * 8);
    const __half2 h01 = *(const __half2*)&raw.x;
    const __half2 h23 = *(const __half2*)&raw.y;
    const float2 x01 = __half22float2(h01);
    const float2 x23 = __half22float2(h23);
    float ps = x01.x * av.x + x01.y * av.y + x23.x * av.z + x23.y * av.w;
    float pd = x01.x * dv.x + x01.y * dv.y + x23.x * dv.z + x23.y * dv.w;
    ps += __shfl_xor(ps, 1); pd += __shfl_xor(pd, 1);
    ps += __shfl_xor(ps, 2); pd += __shfl_xor(pd, 2);
    ps += __shfl_xor(ps, 4); pd += __shfl_xor(pd, 4);
    ps += __shfl_xor(ps, 8); pd += __shfl_xor(pd, 8);
    if ((l & 15) == 0) {
        als[n * HEADS + (l >> 4)] = ps;
        ald[n * HEADS + (l >> 4)] = pd;
    }
}

// ---------------- CSR build ----------------
__global__ void k_hist(const int* __restrict__ ei, int* __restrict__ deg) {
    const int e = blockIdx.x * blockDim.x + threadIdx.x;
    if (e >= N_EDGES) return;
    atomicAdd(&deg[ei[N_EDGES + e]], 1);
}

__global__ void k_scan_part(const int* __restrict__ deg, int* __restrict__ row,
                            int* __restrict__ bsum) {
    __shared__ int sm[256];
    const int tid = threadIdx.x;
    const int i = blockIdx.x * 256 + tid;
    const int v = (i < N_NODES) ? deg[i] : 0;
    sm[tid] = v;
    __syncthreads();
    for (int off = 1; off < 256; off <<= 1) {
        int t = (tid >= off) ? sm[tid - off] : 0;
        __syncthreads();
        sm[tid] += t;
        __syncthreads();
    }
    if (i < N_NODES) row[i] = sm[tid] - v;
    if (tid == 255) bsum[blockIdx.x] = sm[255];
}

__global__ void k_scan_block(int* __restrict__ bsum) {
    __shared__ int sm[256];
    const int tid = threadIdx.x;
    const int v = (tid < NB_SCAN) ? bsum[tid] : 0;
    sm[tid] = v;
    __syncthreads();
    for (int off = 1; off < 256; off <<= 1) {
        int t = (tid >= off) ? sm[tid - off] : 0;
        __syncthreads();
        sm[tid] += t;
        __syncthreads();
    }
    if (tid < NB_SCAN) bsum[tid] = sm[tid] - v;
}

__global__ void k_scan_add(int* __restrict__ row, const int* __restrict__ bsum,
                           int* __restrict__ cur) {
    const int i = blockIdx.x * 256 + threadIdx.x;
    if (i == 0) row[N_NODES] = N_EDGES;
    if (i >= N_NODES) return;
    const int r = row[i] + bsum[blockIdx.x];
    row[i] = r;
    cur[i] = r;
}

__global__ void k_scatter(const int* __restrict__ ei, int* __restrict__ cur,
                          int* __restrict__ esrc) {
    const int e = blockIdx.x * blockDim.x + threadIdx.x;
    if (e >= N_EDGES) return;
    const int s = ei[e], d = ei[N_EDGES + e];
    const int pos = atomicAdd(&cur[d], 1);
    esrc[pos] = s;
}

// ---------------- K3: layer-1 aggregation, wave/node, 4 gathers in flight ----------------
__global__ void k_agg1_h(const int* __restrict__ row, const int* __restrict__ esrc,
                         const float* __restrict__ als, const float* __restrict__ ald,
                         const __half* __restrict__ xh1, float* __restrict__ agg1) {
    const int d = blockIdx.x * 4 + (threadIdx.x >> 6);
    const int lane = threadIdx.x & 63;
    if (d >= N_NODES) return;
    const int hq = lane >> 4;       // head this lane accumulates
    const int he = lane & 3;        // head this lane exponentiates
    const float adh = ald[d * 4 + he];
    const int start = row[d];
    const int total = row[d + 1] - start + 1;   // + self loop
    float acc0 = 0.f, acc1 = 0.f, acc2 = 0.f, acc3 = 0.f;
    float denp = 0.f;
    const size_t lby = (size_t)(lane << 3);
    for (int t0 = 0; t0 < total; t0 += 16) {
        int m = total - t0; if (m > 16) m = 16;
        const int slot = lane >> 2;
        float ev = 0.f; int s = d;
        if (slot < m) {
            const int t = t0 + slot;
            if (t > 0) s = esrc[start + t - 1];
            ev = expf(lrelu(als[s * 4 + he] + adh));
        }
        denp += ev;
        int j = 0;
        for (; j + 4 <= m; j += 4) {
            const int s0 = __shfl(s, (j + 0) * 4);
            const int s1 = __shfl(s, (j + 1) * 4);
            const int s2 = __shfl(s, (j + 2) * 4);
            const int s3 = __shfl(s, (j + 3) * 4);
            const float2 r0 = *(const float2*)((const char*)xh1 + ((size_t)s0 << 9) + lby);
            const float2 r1 = *(const float2*)((const char*)xh1 + ((size_t)s1 << 9) + lby);
            const float2 r2 = *(const float2*)((const char*)xh1 + ((size_t)s2 << 9) + lby);
            const float2 r3 = *(const float2*)((const char*)xh1 + ((size_t)s3 << 9) + lby);
            const float c0 = __shfl(ev, (j + 0) * 4 + hq);
            const float c1 = __shfl(ev, (j + 1) * 4 + hq);
            const float c2 = __shfl(ev, (j + 2) * 4 + hq);
            const float c3 = __shfl(ev, (j + 3) * 4 + hq);
            {
                const float2 a = __half22float2(*(const __half2*)&r0.x);
                const float2 b = __half22float2(*(const __half2*)&r0.y);
                acc0 += c0 * a.x; acc1 += c0 * a.y; acc2 += c0 * b.x; acc3 += c0 * b.y;
            }
            {
                const float2 a = __half22float2(*(const __half2*)&r1.x);
                const float2 b = __half22float2(*(const __half2*)&r1.y);
                acc0 += c1 * a.x; acc1 += c1 * a.y; acc2 += c1 * b.x; acc3 += c1 * b.y;
            }
            {
                const float2 a = __half22float2(*(const __half2*)&r2.x);
                const float2 b = __half22float2(*(const __half2*)&r2.y);
                acc0 += c2 * a.x; acc1 += c2 * a.y; acc2 += c2 * b.x; acc3 += c2 * b.y;
            }
            {
                const float2 a = __half22float2(*(const __half2*)&r3.x);
                const float2 b = __half22float2(*(const __half2*)&r3.y);
                acc0 += c3 * a.x; acc1 += c3 * a.y; acc2 += c3 * b.x; acc3 += c3 * b.y;
            }
        }
        for (; j < m; j++) {
            const float cf = __shfl(ev, j * 4 + hq);
            const int sj   = __shfl(s, j * 4);
            const float2 raw = *(const float2*)((const char*)xh1 + ((size_t)sj << 9) + lby);
            const float2 a = __half22float2(*(const __half2*)&raw.x);
            const float2 b = __half22float2(*(const __half2*)&raw.y);
            acc0 += cf * a.x; acc1 += cf * a.y; acc2 += cf * b.x; acc3 += cf * b.y;
        }
    }
    denp += __shfl_xor(denp, 4);
    denp += __shfl_xor(denp, 8);
    denp += __shfl_xor(denp, 16);
    denp += __shfl_xor(denp, 32);
    const float deninv = 1.f / __shfl(denp, hq);
    acc0 *= deninv; acc1 *= deninv; acc2 *= deninv; acc3 *= deninv;
    acc0 += __shfl_xor(acc0, 16); acc0 += __shfl_xor(acc0, 32);
    acc1 += __shfl_xor(acc1, 16); acc1 += __shfl_xor(acc1, 32);
    acc2 += __shfl_xor(acc2, 16); acc2 += __shfl_xor(acc2, 32);
    acc3 += __shfl_xor(acc3, 16); acc3 += __shfl_xor(acc3, 32);
    if (lane < 16) {
        float4 st = { 0.25f * acc0, 0.25f * acc1, 0.25f * acc2, 0.25f * acc3 };
        *(float4*)(agg1 + (size_t)d * HID + lane * 4) = st;
    }
}

// ---------------- K5: xh2h = half(relu(agg1+b1) @ W2) via MFMA ----------------
__global__ void k_gemm2_mfma(const float* __restrict__ agg1, const float* __restrict__ b1,
                             const __half* __restrict__ w2t, __half* __restrict__ xh2) {
    __shared__ _Float16 ash[64][72];
    __shared__ _Float16 wsh[128][72];
    const int tid = threadIdx.x;
    const int m0 = blockIdx.x * 64;
    // stage relu(agg1+b1) tile: 64 rows x 64 k = 1024 float4
#pragma unroll
    for (int i = 0; i < 4; i++) {
        const int f = tid + i * 256;
        const int r = f >> 4;
        const int k4 = (f & 15) * 4;
        const int gr = (m0 + r < N_NODES) ? (m0 + r) : (N_NODES - 1);
        float4 v = *(const float4*)(agg1 + (size_t)gr * HID + k4);
        v.x += b1[k4 + 0]; v.y += b1[k4 + 1];
        v.z += b1[k4 + 2]; v.w += b1[k4 + 3];
        v.x = v.x > 0.f ? v.x : 0.f;
        v.y = v.y > 0.f ? v.y : 0.f;
        v.z = v.z > 0.f ? v.z : 0.f;
        v.w = v.w > 0.f ? v.w : 0.f;
        half4v hv = { (_Float16)v.x, (_Float16)v.y, (_Float16)v.z, (_Float16)v.w };
        *(half4v*)&ash[r][k4] = hv;
    }
    // stage w2t: 128 x 64 halves = 1024 half8
#pragma unroll
    for (int i = 0; i < 4; i++) {
        const int u = tid + i * 256;
        const int r = u >> 3;
        const int k = (u & 7) * 8;
        *(half8v*)&wsh[r][k] = *(const half8v*)(w2t + (size_t)r * HID + k);
    }
    __syncthreads();
    const int w = tid >> 6, l = tid & 63;
    const int lr = l & 15, lk = (l >> 4) * 8;
    float4v acc[8];
#pragma unroll
    for (int c = 0; c < 8; c++) acc[c] = (float4v){0.f, 0.f, 0.f, 0.f};
#pragma unroll
    for (int k0 = 0; k0 < HID; k0 += 32) {
        const half8v a = *(const half8v*)&ash[w * 16 + lr][k0 + lk];
#pragma unroll
        for (int c = 0; c < 8; c++) {
            const half8v b = *(const half8v*)&wsh[c * 16 + lr][k0 + lk];
            acc[c] = __builtin_amdgcn_mfma_f32_16x16x32_f16(a, b, acc[c], 0, 0, 0);
        }
    }
    const int rbase = m0 + w * 16 + (l >> 4) * 4;
#pragma unroll
    for (int r = 0; r < 4; r++) {
        const int node = rbase + r;
        if (node < N_NODES) {
            __half* p = xh2 + (size_t)node * (HEADS * HID2) + lr;
#pragma unroll
            for (int c = 0; c < 8; c++) p[c * 16] = __float2half(acc[c][r]);
        }
    }
}

// ---------------- K5b: als2/ald2 from xh2h ----------------
__global__ void k_attn2(const __half* __restrict__ xh2, const float* __restrict__ as2,
                        const float* __restrict__ ad2, float* __restrict__ als,
                        float* __restrict__ ald) {
    const int n = blockIdx.x * 4 + (threadIdx.x >> 6);
    const int l = threadIdx.x & 63;
    if (n >= N_NODES) return;
    // lane l covers cols 2l..2l+1; head = l>>4
    const float2 av = *(const float2*)(as2 + l * 2);
    const float2 dv = *(const float2*)(ad2 + l * 2);
    const __half2 hv = *(const __half2*)((const char*)xh2 + (size_t)n * 256 + l * 4);
    const float2 xv = __half22float2(hv);
    float ps = xv.x * av.x + xv.y * av.y;
    float pd = xv.x * dv.x + xv.y * dv.y;
    ps += __shfl_xor(ps, 1); pd += __shfl_xor(pd, 1);
    ps += __shfl_xor(ps, 2); pd += __shfl_xor(pd, 2);
    ps += __shfl_xor(ps, 4); pd += __shfl_xor(pd, 4);
    ps += __shfl_xor(ps, 8); pd += __shfl_xor(pd, 8);
    if ((l & 15) == 0) {
        als[n * HEADS + (l >> 4)] = ps;
        ald[n * HEADS + (l >> 4)] = pd;
    }
}

// ---------------- K7: layer-2 aggregation, wave/node, 4 gathers in flight ----------------
__global__ void k_agg2_h(const int* __restrict__ row, const int* __restrict__ esrc,
                         const float* __restrict__ als, const float* __restrict__ ald,
                         const __half* __restrict__ xh2, float* __restrict__ agg2) {
    const int d = blockIdx.x * 4 + (threadIdx.x >> 6);
    const int lane = threadIdx.x & 63;
    if (d >= N_NODES) return;
    const int hq = lane >> 4;
    const int he = lane & 3;
    const float adh = ald[d * 4 + he];
    const int start = row[d];
    const int total = row[d + 1] - start + 1;   // + self loop
    float acc0 = 0.f, acc1 = 0.f;
    float denp = 0.f;
    const size_t lby = (size_t)(lane << 2);
    for (int t0 = 0; t0 < total; t0 += 16) {
        int m = total - t0; if (m > 16) m = 16;
        const int slot = lane >> 2;
        float ev = 0.f; int s = d;
        if (slot < m) {
            const int t = t0 + slot;
            if (t > 0) s = esrc[start + t - 1];
            ev = expf(lrelu(als[s * 4 + he] + adh));
        }
        denp += ev;
        int j = 0;
        for (; j + 4 <= m; j += 4) {
            const int s0 = __shfl(s, (j + 0) * 4);
            const int s1 = __shfl(s, (j + 1) * 4);
            const int s2 = __shfl(s, (j + 2) * 4);
            const int s3 = __shfl(s, (j + 3) * 4);
            const __half2 r0 = *(const __half2*)((const char*)xh2 + ((size_t)s0 << 8) + lby);
            const __half2 r1 = *(const __half2*)((const char*)xh2 + ((size_t)s1 << 8) + lby);
            const __half2 r2 = *(const __half2*)((const char*)xh2 + ((size_t)s2 << 8) + lby);
            const __half2 r3 = *(const __half2*)((const char*)xh2 + ((size_t)s3 << 8) + lby);
            const float c0 = __shfl(ev, (j + 0) * 4 + hq);
            const float c1 = __shfl(ev, (j + 1) * 4 + hq);
            const float c2 = __shfl(ev, (j + 2) * 4 + hq);
            const float c3 = __shfl(ev, (j + 3) * 4 + hq);
            { const float2 xv = __half22float2(r0); acc0 += c0 * xv.x; acc1 += c0 * xv.y; }
            { const float2 xv = __half22float2(r1); acc0 += c1 * xv.x; acc1 += c1 * xv.y; }
            { const float2 xv = __half22float2(r2); acc0 += c2 * xv.x; acc1 += c2 * xv.y; }
            { const float2 xv = __half22float2(r3); acc0 += c3 * xv.x; acc1 += c3 * xv.y; }
        }
        for (; j < m; j++) {
            const float cf = __shfl(ev, j * 4 + hq);
            const int sj   = __shfl(s, j * 4);
            const __half2 hv = *(const __half2*)((const char*)xh2 + ((size_t)sj << 8) + lby);
            const float2 xv = __half22float2(hv);
            acc0 += cf * xv.x; acc1 += cf * xv.y;
        }
    }
    denp += __shfl_xor(denp, 4);
    denp += __shfl_xor(denp, 8);
    denp += __shfl_xor(denp, 16);
    denp += __shfl_xor(denp, 32);
    const float deninv = 1.f / __shfl(denp, hq);
    acc0 *= deninv; acc1 *= deninv;
    acc0 += __shfl_xor(acc0, 16); acc0 += __shfl_xor(acc0, 32);
    acc1 += __shfl_xor(acc1, 16); acc1 += __shfl_xor(acc1, 32);
    if (lane < 16) {
        float2 st = { 0.25f * acc0, 0.25f * acc1 };
        *(float2*)(agg2 + (size_t)d * HID2 + lane * 2) = st;
    }
}

// ---------------- K8: final projections ----------------
#define NPB3 4
__global__ void k_final(const float* __restrict__ agg2, const float* __restrict__ b2,
                        const float* __restrict__ Wmu, const float* __restrict__ bmu,
                        const float* __restrict__ Wlv, const float* __restrict__ blv,
                        float* __restrict__ out) {
    __shared__ float hs[NPB3][HID2];
    const int tid = threadIdx.x;              // 256
    const int n0  = blockIdx.x * NPB3;
    if (tid < NPB3 * HID2) {
        int ni = tid >> 5, ci = tid & 31;
        float v = agg2[(size_t)(n0 + ni) * HID2 + ci] + b2[ci];
        hs[ni][ci] = v > 0.f ? v : 0.f;
    }
    __syncthreads();
    const int ni = tid >> 6;
    const int which = (tid >> 5) & 1;
    const int l = tid & 31;
    const float* W = which ? Wlv : Wmu;
    const float* b = which ? blv : bmu;
    float acc = b[l];
#pragma unroll
    for (int c = 0; c < HID2; c++) acc += hs[ni][c] * W[c * LATENT + l];
    const int n = n0 + ni;
    out[(size_t)which * N_NODES * LATENT + (size_t)n * LATENT + l] = acc;
}

extern "C" void kernel_launch(void* const* d_in, const int* in_sizes, int n_in,
                              void* d_out, int out_size, void* d_ws, size_t ws_size,
                              hipStream_t stream) {
    const float* x    = (const float*)d_in[0];
    const int*   ei   = (const int*)d_in[1];
    const float* W1   = (const float*)d_in[2];
    const float* as1  = (const float*)d_in[3];
    const float* ad1  = (const float*)d_in[4];
    const float* b1   = (const float*)d_in[5];
    const float* W2   = (const float*)d_in[6];
    const float* as2  = (const float*)d_in[7];
    const float* ad2  = (const float*)d_in[8];
    const float* b2   = (const float*)d_in[9];
    const float* Wmu  = (const float*)d_in[10];
    const float* bmu  = (const float*)d_in[11];
    const float* Wlv  = (const float*)d_in[12];
    const float* blv  = (const float*)d_in[13];
    float* out = (float*)d_out;
    float* ws  = (float*)d_ws;

    __half* xh1h = (__half*)(ws + OFF_XH1H);
    __half* xh2h = (__half*)(ws + OFF_XH2H);
    __half* w1th = (__half*)(ws + OFF_W1TH);
    __half* w2th = (__half*)(ws + OFF_W2TH);
    float* als1 = ws + OFF_ALS1;
    float* ald1 = ws + OFF_ALD1;
    float* agg1 = ws + OFF_AGG1;
    float* als2 = ws + OFF_ALS2;
    float* ald2 = ws + OFF_ALD2;
    float* agg2 = ws + OFF_AGG2;
    int* deg  = (int*)(ws + OFF_DEG);
    int* rowp = (int*)(ws + OFF_ROW);
    int* bsum = (int*)(ws + OFF_BSUM);
    int* esrc = (int*)(ws + OFF_ESRC);

    hipMemsetAsync(deg, 0, N_NODES * sizeof(int), stream);

    k_cvt_w<<<160, 256, 0, stream>>>(W1, W2, w1th, w2th);
    k_gemm1_mfma<<<782 * 4, 256, 0, stream>>>(x, w1th, xh1h);
    k_attn1<<<(N_NODES + 3) / 4, 256, 0, stream>>>(xh1h, as1, ad1, als1, ald1);

    // CSR build (dst-major)
    k_hist<<<(N_EDGES + 255) / 256, 256, 0, stream>>>(ei, deg);
    k_scan_part<<<NB_SCAN, 256, 0, stream>>>(deg, rowp, bsum);
    k_scan_block<<<1, 256, 0, stream>>>(bsum);
    k_scan_add<<<NB_SCAN, 256, 0, stream>>>(rowp, bsum, deg /*cursor*/);
    k_scatter<<<(N_EDGES + 255) / 256, 256, 0, stream>>>(ei, deg /*cursor*/, esrc);

    k_agg1_h<<<(N_NODES + 3) / 4, 256, 0, stream>>>(rowp, esrc, als1, ald1, xh1h, agg1);

    k_gemm2_mfma<<<(N_NODES + 63) / 64, 256, 0, stream>>>(agg1, b1, w2th, xh2h);
    k_attn2<<<(N_NODES + 3) / 4, 256, 0, stream>>>(xh2h, as2, ad2, als2, ald2);

    k_agg2_h<<<(N_NODES + 3) / 4, 256, 0, stream>>>(rowp, esrc, als2, ald2, xh2h, agg2);

    k_final<<<N_NODES / NPB3, 256, 0, stream>>>(agg2, b2, Wmu, bmu, Wlv, blv, out);
}

// Round 8
// 251.332 us; speedup vs baseline: 1.4864x; 1.0651x over previous
//
#include <hip/hip_runtime.h>
#include <hip/hip_fp16.h>

#define N_NODES 50000
#define N_EDGES 800000
#define IN_DIM  128
#define HID     64
#define HID2    32
#define HEADS   4
#define LATENT  32
#define NEG_SLOPE 0.2f

typedef _Float16 half8v __attribute__((ext_vector_type(8)));
typedef _Float16 half4v __attribute__((ext_vector_type(4)));
typedef float    float4v __attribute__((ext_vector_type(4)));

// ---------------- workspace layout (float offsets) ----------------
#define OFF_XH1H  ((size_t)0)            //  6,400,000 (half storage)
#define OFF_XH2H  ((size_t)0)            //  3,200,000 (overlay, xh1 dead)
#define OFF_ALS2  ((size_t)8000000)      //    200,000
#define OFF_ALD2  ((size_t)8200000)      //    200,000
#define OFF_AGG1  ((size_t)8400000)      //  3,200,000
#define OFF_ALS1  ((size_t)11600000)     //    200,000
#define OFF_ALD1  ((size_t)11800000)     //    200,000
// CSR (ints in float slots)
#define OFF_DEG   ((size_t)12000000)     //     50,000 (reused as scatter cursor)
#define OFF_ROW   ((size_t)12050000)     //     50,001
#define OFF_BSUM  ((size_t)12100004)     //        256
#define OFF_ESRC  ((size_t)12100260)     //    800,000
#define OFF_W1TH  ((size_t)12900260)     //     16,384 float slots (32768 halves)
#define OFF_W2TH  ((size_t)12916644)     //      4,096 float slots (8192 halves)

#define NB_SCAN ((N_NODES + 255) / 256)  // 196

__device__ __forceinline__ float lrelu(float v) {
    return v > 0.f ? v : NEG_SLOPE * v;
}

// ---------------- K0: weight fp16 transposes ----------------
__global__ void k_cvt_w(const float* __restrict__ W1, const float* __restrict__ W2,
                        __half* __restrict__ w1t, __half* __restrict__ w2t) {
    const int t = blockIdx.x * 256 + threadIdx.x;
    if (t < 32768) {
        const int k = t >> 8, n = t & 255;
        w1t[n * IN_DIM + k] = __float2half(W1[t]);
    } else if (t < 32768 + 8192) {
        const int t2 = t - 32768;
        const int k = t2 >> 7, n = t2 & 127;
        w2t[n * HID + k] = __float2half(W2[t2]);
    }
}

// ---------------- K1: xh1h = half(x @ W1) via MFMA + fused als1/ald1 ----------------
// Col-block n0 covers cols [n0, n0+64) == head n0/64, so this block computes the
// COMPLETE attention logits for its (rows, head) from pre-rounding fp32 accs.
__global__ void k_gemm1_mfma(const float* __restrict__ x, const __half* __restrict__ w1t,
                             const float* __restrict__ as1, const float* __restrict__ ad1,
                             __half* __restrict__ xh1, float* __restrict__ als,
                             float* __restrict__ ald) {
    __shared__ _Float16 xsh[64][136];
    __shared__ _Float16 wsh[64][136];
    const int tid = threadIdx.x;
    const int mb = blockIdx.x >> 2;
    const int n0 = (blockIdx.x & 3) * 64;
    const int m0 = mb * 64;
#pragma unroll
    for (int i = 0; i < 8; i++) {
        const int f = tid + i * 256;
        const int r = f >> 5;
        const int k = (f & 31) * 4;
        const int gr = (m0 + r < N_NODES) ? (m0 + r) : (N_NODES - 1);
        const float4 xv = *(const float4*)(x + (size_t)gr * IN_DIM + k);
        half4v hv = { (_Float16)xv.x, (_Float16)xv.y, (_Float16)xv.z, (_Float16)xv.w };
        *(half4v*)&xsh[r][k] = hv;
    }
#pragma unroll
    for (int i = 0; i < 4; i++) {
        const int u = tid + i * 256;
        const int r = u >> 4;
        const int k = (u & 15) * 8;
        *(half8v*)&wsh[r][k] = *(const half8v*)(w1t + (size_t)(n0 + r) * IN_DIM + k);
    }
    __syncthreads();
    const int w = tid >> 6, l = tid & 63;
    const int lr = l & 15;
    const int lk = (l >> 4) * 8;
    float4v acc0 = {0.f,0.f,0.f,0.f}, acc1 = {0.f,0.f,0.f,0.f};
    float4v acc2 = {0.f,0.f,0.f,0.f}, acc3 = {0.f,0.f,0.f,0.f};
#pragma unroll
    for (int k0 = 0; k0 < IN_DIM; k0 += 32) {
        const half8v a  = *(const half8v*)&xsh[w * 16 + lr][k0 + lk];
        const half8v b0 = *(const half8v*)&wsh[ 0 + lr][k0 + lk];
        const half8v b1 = *(const half8v*)&wsh[16 + lr][k0 + lk];
        const half8v b2 = *(const half8v*)&wsh[32 + lr][k0 + lk];
        const half8v b3 = *(const half8v*)&wsh[48 + lr][k0 + lk];
        acc0 = __builtin_amdgcn_mfma_f32_16x16x32_f16(a, b0, acc0, 0, 0, 0);
        acc1 = __builtin_amdgcn_mfma_f32_16x16x32_f16(a, b1, acc1, 0, 0, 0);
        acc2 = __builtin_amdgcn_mfma_f32_16x16x32_f16(a, b2, acc2, 0, 0, 0);
        acc3 = __builtin_amdgcn_mfma_f32_16x16x32_f16(a, b3, acc3, 0, 0, 0);
    }
    const int rbase = m0 + w * 16 + (l >> 4) * 4;
    const int cbase = n0 + lr;
#pragma unroll
    for (int r = 0; r < 4; r++) {
        const int node = rbase + r;
        if (node < N_NODES) {
            __half* p = xh1 + (size_t)node * (HEADS * HID) + cbase;
            p[0]  = __float2half(acc0[r]);
            p[16] = __float2half(acc1[r]);
            p[32] = __float2half(acc2[r]);
            p[48] = __float2half(acc3[r]);
        }
    }
    // fused attention logits for head h = n0>>6
    const int h = n0 >> 6;
    const float a0 = as1[(h << 6) + lr +  0], a1 = as1[(h << 6) + lr + 16];
    const float a2 = as1[(h << 6) + lr + 32], a3 = as1[(h << 6) + lr + 48];
    const float d0 = ad1[(h << 6) + lr +  0], d1 = ad1[(h << 6) + lr + 16];
    const float d2 = ad1[(h << 6) + lr + 32], d3 = ad1[(h << 6) + lr + 48];
#pragma unroll
    for (int r = 0; r < 4; r++) {
        float ps = acc0[r] * a0 + acc1[r] * a1 + acc2[r] * a2 + acc3[r] * a3;
        float pd = acc0[r] * d0 + acc1[r] * d1 + acc2[r] * d2 + acc3[r] * d3;
        ps += __shfl_xor(ps, 1); pd += __shfl_xor(pd, 1);
        ps += __shfl_xor(ps, 2); pd += __shfl_xor(pd, 2);
        ps += __shfl_xor(ps, 4); pd += __shfl_xor(pd, 4);
        ps += __shfl_xor(ps, 8); pd += __shfl_xor(pd, 8);
        if (lr == 0) {
            const int node = rbase + r;
            if (node < N_NODES) {
                als[node * HEADS + h] = ps;
                ald[node * HEADS + h] = pd;
            }
        }
    }
}

// ---------------- CSR build ----------------
__global__ void k_hist(const int* __restrict__ ei, int* __restrict__ deg) {
    const int e = blockIdx.x * blockDim.x + threadIdx.x;
    if (e >= N_EDGES) return;
    atomicAdd(&deg[ei[N_EDGES + e]], 1);
}

__global__ void k_scan_part(const int* __restrict__ deg, int* __restrict__ row,
                            int* __restrict__ bsum) {
    __shared__ int sm[256];
    const int tid = threadIdx.x;
    const int i = blockIdx.x * 256 + tid;
    const int v = (i < N_NODES) ? deg[i] : 0;
    sm[tid] = v;
    __syncthreads();
    for (int off = 1; off < 256; off <<= 1) {
        int t = (tid >= off) ? sm[tid - off] : 0;
        __syncthreads();
        sm[tid] += t;
        __syncthreads();
    }
    if (i < N_NODES) row[i] = sm[tid] - v;
    if (tid == 255) bsum[blockIdx.x] = sm[255];
}

__global__ void k_scan_block(int* __restrict__ bsum) {
    __shared__ int sm[256];
    const int tid = threadIdx.x;
    const int v = (tid < NB_SCAN) ? bsum[tid] : 0;
    sm[tid] = v;
    __syncthreads();
    for (int off = 1; off < 256; off <<= 1) {
        int t = (tid >= off) ? sm[tid - off] : 0;
        __syncthreads();
        sm[tid] += t;
        __syncthreads();
    }
    if (tid < NB_SCAN) bsum[tid] = sm[tid] - v;
}

__global__ void k_scan_add(int* __restrict__ row, const int* __restrict__ bsum,
                           int* __restrict__ cur) {
    const int i = blockIdx.x * 256 + threadIdx.x;
    if (i == 0) row[N_NODES] = N_EDGES;
    if (i >= N_NODES) return;
    const int r = row[i] + bsum[blockIdx.x];
    row[i] = r;
    cur[i] = r;
}

__global__ void k_scatter(const int* __restrict__ ei, int* __restrict__ cur,
                          int* __restrict__ esrc) {
    const int e = blockIdx.x * blockDim.x + threadIdx.x;
    if (e >= N_EDGES) return;
    const int s = ei[e], d = ei[N_EDGES + e];
    const int pos = atomicAdd(&cur[d], 1);
    esrc[pos] = s;
}

// ---------------- K3: layer-1 aggregation, wave/node, 8 gathers in flight ----------------
__global__ void k_agg1_h(const int* __restrict__ row, const int* __restrict__ esrc,
                         const float* __restrict__ als, const float* __restrict__ ald,
                         const __half* __restrict__ xh1, float* __restrict__ agg1) {
    const int d = blockIdx.x * 4 + (threadIdx.x >> 6);
    const int lane = threadIdx.x & 63;
    if (d >= N_NODES) return;
    const int hq = lane >> 4;
    const int he = lane & 3;
    const float adh = ald[d * 4 + he];
    const int start = row[d];
    const int total = row[d + 1] - start + 1;   // + self loop
    float acc0 = 0.f, acc1 = 0.f, acc2 = 0.f, acc3 = 0.f;
    float denp = 0.f;
    const size_t lby = (size_t)(lane << 3);
    for (int t0 = 0; t0 < total; t0 += 16) {
        int m = total - t0; if (m > 16) m = 16;
        const int slot = lane >> 2;
        float ev = 0.f; int s = d;
        if (slot < m) {
            const int t = t0 + slot;
            if (t > 0) s = esrc[start + t - 1];
            ev = expf(lrelu(als[s * 4 + he] + adh));
        }
        denp += ev;
        int j = 0;
        for (; j + 8 <= m; j += 8) {
            int ss[8]; float cc[8]; float2 rr[8];
#pragma unroll
            for (int u = 0; u < 8; u++) ss[u] = __shfl(s, (j + u) * 4);
#pragma unroll
            for (int u = 0; u < 8; u++)
                rr[u] = *(const float2*)((const char*)xh1 + ((size_t)ss[u] << 9) + lby);
#pragma unroll
            for (int u = 0; u < 8; u++) cc[u] = __shfl(ev, (j + u) * 4 + hq);
#pragma unroll
            for (int u = 0; u < 8; u++) {
                const float2 a = __half22float2(*(const __half2*)&rr[u].x);
                const float2 b = __half22float2(*(const __half2*)&rr[u].y);
                acc0 += cc[u] * a.x; acc1 += cc[u] * a.y;
                acc2 += cc[u] * b.x; acc3 += cc[u] * b.y;
            }
        }
        for (; j + 4 <= m; j += 4) {
            int ss[4]; float cc[4]; float2 rr[4];
#pragma unroll
            for (int u = 0; u < 4; u++) ss[u] = __shfl(s, (j + u) * 4);
#pragma unroll
            for (int u = 0; u < 4; u++)
                rr[u] = *(const float2*)((const char*)xh1 + ((size_t)ss[u] << 9) + lby);
#pragma unroll
            for (int u = 0; u < 4; u++) cc[u] = __shfl(ev, (j + u) * 4 + hq);
#pragma unroll
            for (int u = 0; u < 4; u++) {
                const float2 a = __half22float2(*(const __half2*)&rr[u].x);
                const float2 b = __half22float2(*(const __half2*)&rr[u].y);
                acc0 += cc[u] * a.x; acc1 += cc[u] * a.y;
                acc2 += cc[u] * b.x; acc3 += cc[u] * b.y;
            }
        }
        for (; j < m; j++) {
            const float cf = __shfl(ev, j * 4 + hq);
            const int sj   = __shfl(s, j * 4);
            const float2 raw = *(const float2*)((const char*)xh1 + ((size_t)sj << 9) + lby);
            const float2 a = __half22float2(*(const __half2*)&raw.x);
            const float2 b = __half22float2(*(const __half2*)&raw.y);
            acc0 += cf * a.x; acc1 += cf * a.y; acc2 += cf * b.x; acc3 += cf * b.y;
        }
    }
    denp += __shfl_xor(denp, 4);
    denp += __shfl_xor(denp, 8);
    denp += __shfl_xor(denp, 16);
    denp += __shfl_xor(denp, 32);
    const float deninv = 1.f / __shfl(denp, hq);
    acc0 *= deninv; acc1 *= deninv; acc2 *= deninv; acc3 *= deninv;
    acc0 += __shfl_xor(acc0, 16); acc0 += __shfl_xor(acc0, 32);
    acc1 += __shfl_xor(acc1, 16); acc1 += __shfl_xor(acc1, 32);
    acc2 += __shfl_xor(acc2, 16); acc2 += __shfl_xor(acc2, 32);
    acc3 += __shfl_xor(acc3, 16); acc3 += __shfl_xor(acc3, 32);
    if (lane < 16) {
        float4 st = { 0.25f * acc0, 0.25f * acc1, 0.25f * acc2, 0.25f * acc3 };
        *(float4*)(agg1 + (size_t)d * HID + lane * 4) = st;
    }
}

// ---------------- K5: xh2h = half(relu(agg1+b1) @ W2) via MFMA + fused als2/ald2 ----------------
__global__ void k_gemm2_mfma(const float* __restrict__ agg1, const float* __restrict__ b1,
                             const __half* __restrict__ w2t, const float* __restrict__ as2,
                             const float* __restrict__ ad2, __half* __restrict__ xh2,
                             float* __restrict__ als, float* __restrict__ ald) {
    __shared__ _Float16 ash[64][72];
    __shared__ _Float16 wsh[128][72];
    const int tid = threadIdx.x;
    const int m0 = blockIdx.x * 64;
#pragma unroll
    for (int i = 0; i < 4; i++) {
        const int f = tid + i * 256;
        const int r = f >> 4;
        const int k4 = (f & 15) * 4;
        const int gr = (m0 + r < N_NODES) ? (m0 + r) : (N_NODES - 1);
        float4 v = *(const float4*)(agg1 + (size_t)gr * HID + k4);
        v.x += b1[k4 + 0]; v.y += b1[k4 + 1];
        v.z += b1[k4 + 2]; v.w += b1[k4 + 3];
        v.x = v.x > 0.f ? v.x : 0.f;
        v.y = v.y > 0.f ? v.y : 0.f;
        v.z = v.z > 0.f ? v.z : 0.f;
        v.w = v.w > 0.f ? v.w : 0.f;
        half4v hv = { (_Float16)v.x, (_Float16)v.y, (_Float16)v.z, (_Float16)v.w };
        *(half4v*)&ash[r][k4] = hv;
    }
#pragma unroll
    for (int i = 0; i < 4; i++) {
        const int u = tid + i * 256;
        const int r = u >> 3;
        const int k = (u & 7) * 8;
        *(half8v*)&wsh[r][k] = *(const half8v*)(w2t + (size_t)r * HID + k);
    }
    __syncthreads();
    const int w = tid >> 6, l = tid & 63;
    const int lr = l & 15, lk = (l >> 4) * 8;
    float4v acc[8];
#pragma unroll
    for (int c = 0; c < 8; c++) acc[c] = (float4v){0.f, 0.f, 0.f, 0.f};
#pragma unroll
    for (int k0 = 0; k0 < HID; k0 += 32) {
        const half8v a = *(const half8v*)&ash[w * 16 + lr][k0 + lk];
#pragma unroll
        for (int c = 0; c < 8; c++) {
            const half8v b = *(const half8v*)&wsh[c * 16 + lr][k0 + lk];
            acc[c] = __builtin_amdgcn_mfma_f32_16x16x32_f16(a, b, acc[c], 0, 0, 0);
        }
    }
    const int rbase = m0 + w * 16 + (l >> 4) * 4;
#pragma unroll
    for (int r = 0; r < 4; r++) {
        const int node = rbase + r;
        if (node < N_NODES) {
            __half* p = xh2 + (size_t)node * (HEADS * HID2) + lr;
#pragma unroll
            for (int c = 0; c < 8; c++) p[c * 16] = __float2half(acc[c][r]);
        }
    }
    // fused attention logits: col = lr + 16c, head = c>>1, col-in-head = lr + 16*(c&1)
    float av[8], dv[8];
#pragma unroll
    for (int c = 0; c < 8; c++) {
        const int hh = c >> 1, cih = lr + 16 * (c & 1);
        av[c] = as2[hh * HID2 + cih];
        dv[c] = ad2[hh * HID2 + cih];
    }
#pragma unroll
    for (int r = 0; r < 4; r++) {
        float ps0 = acc[0][r] * av[0] + acc[1][r] * av[1];
        float ps1 = acc[2][r] * av[2] + acc[3][r] * av[3];
        float ps2 = acc[4][r] * av[4] + acc[5][r] * av[5];
        float ps3 = acc[6][r] * av[6] + acc[7][r] * av[7];
        float pd0 = acc[0][r] * dv[0] + acc[1][r] * dv[1];
        float pd1 = acc[2][r] * dv[2] + acc[3][r] * dv[3];
        float pd2 = acc[4][r] * dv[4] + acc[5][r] * dv[5];
        float pd3 = acc[6][r] * dv[6] + acc[7][r] * dv[7];
#pragma unroll
        for (int off = 1; off <= 8; off <<= 1) {
            ps0 += __shfl_xor(ps0, off); ps1 += __shfl_xor(ps1, off);
            ps2 += __shfl_xor(ps2, off); ps3 += __shfl_xor(ps3, off);
            pd0 += __shfl_xor(pd0, off); pd1 += __shfl_xor(pd1, off);
            pd2 += __shfl_xor(pd2, off); pd3 += __shfl_xor(pd3, off);
        }
        if (lr == 0) {
            const int node = rbase + r;
            if (node < N_NODES) {
                float4 sv = { ps0, ps1, ps2, ps3 };
                float4 dvv = { pd0, pd1, pd2, pd3 };
                *(float4*)(als + (size_t)node * HEADS) = sv;
                *(float4*)(ald + (size_t)node * HEADS) = dvv;
            }
        }
    }
}

// ---------------- K7: layer-2 aggregation + fused final projections ----------------
__global__ void k_agg2_final(const int* __restrict__ row, const int* __restrict__ esrc,
                             const float* __restrict__ als, const float* __restrict__ ald,
                             const __half* __restrict__ xh2, const float* __restrict__ b2,
                             const float* __restrict__ Wmu, const float* __restrict__ bmu,
                             const float* __restrict__ Wlv, const float* __restrict__ blv,
                             float* __restrict__ out) {
    const int d = blockIdx.x * 4 + (threadIdx.x >> 6);
    const int lane = threadIdx.x & 63;
    if (d >= N_NODES) return;
    const int hq = lane >> 4;
    const int he = lane & 3;
    const float adh = ald[d * 4 + he];
    const int start = row[d];
    const int total = row[d + 1] - start + 1;   // + self loop
    float acc0 = 0.f, acc1 = 0.f;
    float denp = 0.f;
    const size_t lby = (size_t)(lane << 2);
    for (int t0 = 0; t0 < total; t0 += 16) {
        int m = total - t0; if (m > 16) m = 16;
        const int slot = lane >> 2;
        float ev = 0.f; int s = d;
        if (slot < m) {
            const int t = t0 + slot;
            if (t > 0) s = esrc[start + t - 1];
            ev = expf(lrelu(als[s * 4 + he] + adh));
        }
        denp += ev;
        int j = 0;
        for (; j + 8 <= m; j += 8) {
            int ss[8]; float cc[8]; __half2 rr[8];
#pragma unroll
            for (int u = 0; u < 8; u++) ss[u] = __shfl(s, (j + u) * 4);
#pragma unroll
            for (int u = 0; u < 8; u++)
                rr[u] = *(const __half2*)((const char*)xh2 + ((size_t)ss[u] << 8) + lby);
#pragma unroll
            for (int u = 0; u < 8; u++) cc[u] = __shfl(ev, (j + u) * 4 + hq);
#pragma unroll
            for (int u = 0; u < 8; u++) {
                const float2 xv = __half22float2(rr[u]);
                acc0 += cc[u] * xv.x; acc1 += cc[u] * xv.y;
            }
        }
        for (; j + 4 <= m; j += 4) {
            int ss[4]; float cc[4]; __half2 rr[4];
#pragma unroll
            for (int u = 0; u < 4; u++) ss[u] = __shfl(s, (j + u) * 4);
#pragma unroll
            for (int u = 0; u < 4; u++)
                rr[u] = *(const __half2*)((const char*)xh2 + ((size_t)ss[u] << 8) + lby);
#pragma unroll
            for (int u = 0; u < 4; u++) cc[u] = __shfl(ev, (j + u) * 4 + hq);
#pragma unroll
            for (int u = 0; u < 4; u++) {
                const float2 xv = __half22float2(rr[u]);
                acc0 += cc[u] * xv.x; acc1 += cc[u] * xv.y;
            }
        }
        for (; j < m; j++) {
            const float cf = __shfl(ev, j * 4 + hq);
            const int sj   = __shfl(s, j * 4);
            const __half2 hv = *(const __half2*)((const char*)xh2 + ((size_t)sj << 8) + lby);
            const float2 xv = __half22float2(hv);
            acc0 += cf * xv.x; acc1 += cf * xv.y;
        }
    }
    denp += __shfl_xor(denp, 4);
    denp += __shfl_xor(denp, 8);
    denp += __shfl_xor(denp, 16);
    denp += __shfl_xor(denp, 32);
    const float deninv = 1.f / __shfl(denp, hq);
    acc0 *= deninv; acc1 *= deninv;
    acc0 += __shfl_xor(acc0, 16); acc0 += __shfl_xor(acc0, 32);
    acc1 += __shfl_xor(acc1, 16); acc1 += __shfl_xor(acc1, 32);
    // every lane now holds the head-summed value for col pair (lane&15)
    const int cp = lane & 15;
    float h0 = 0.25f * acc0 + b2[2 * cp];
    float h1 = 0.25f * acc1 + b2[2 * cp + 1];
    h0 = h0 > 0.f ? h0 : 0.f;
    h1 = h1 > 0.f ? h1 : 0.f;
    // dual 32x32 GEMV: lanes 0-31 -> mu, lanes 32-63 -> logvar
    const int jj = lane & 31;
    const bool lv = lane >= 32;
    const float* Wp = lv ? Wlv : Wmu;
    const float* bp = lv ? blv : bmu;
    float o = bp[jj];
#pragma unroll
    for (int k = 0; k < 16; k++) {
        const float e0 = __shfl(h0, k);
        const float e1 = __shfl(h1, k);
        o += e0 * Wp[(2 * k) * LATENT + jj] + e1 * Wp[(2 * k + 1) * LATENT + jj];
    }
    out[(lv ? (size_t)N_NODES * LATENT : (size_t)0) + (size_t)d * LATENT + jj] = o;
}

extern "C" void kernel_launch(void* const* d_in, const int* in_sizes, int n_in,
                              void* d_out, int out_size, void* d_ws, size_t ws_size,
                              hipStream_t stream) {
    const float* x    = (const float*)d_in[0];
    const int*   ei   = (const int*)d_in[1];
    const float* W1   = (const float*)d_in[2];
    const float* as1  = (const float*)d_in[3];
    const float* ad1  = (const float*)d_in[4];
    const float* b1   = (const float*)d_in[5];
    const float* W2   = (const float*)d_in[6];
    const float* as2  = (const float*)d_in[7];
    const float* ad2  = (const float*)d_in[8];
    const float* b2   = (const float*)d_in[9];
    const float* Wmu  = (const float*)d_in[10];
    const float* bmu  = (const float*)d_in[11];
    const float* Wlv  = (const float*)d_in[12];
    const float* blv  = (const float*)d_in[13];
    float* out = (float*)d_out;
    float* ws  = (float*)d_ws;

    __half* xh1h = (__half*)(ws + OFF_XH1H);
    __half* xh2h = (__half*)(ws + OFF_XH2H);
    __half* w1th = (__half*)(ws + OFF_W1TH);
    __half* w2th = (__half*)(ws + OFF_W2TH);
    float* als1 = ws + OFF_ALS1;
    float* ald1 = ws + OFF_ALD1;
    float* agg1 = ws + OFF_AGG1;
    float* als2 = ws + OFF_ALS2;
    float* ald2 = ws + OFF_ALD2;
    int* deg  = (int*)(ws + OFF_DEG);
    int* rowp = (int*)(ws + OFF_ROW);
    int* bsum = (int*)(ws + OFF_BSUM);
    int* esrc = (int*)(ws + OFF_ESRC);

    hipMemsetAsync(deg, 0, N_NODES * sizeof(int), stream);

    k_cvt_w<<<160, 256, 0, stream>>>(W1, W2, w1th, w2th);
    k_gemm1_mfma<<<782 * 4, 256, 0, stream>>>(x, w1th, as1, ad1, xh1h, als1, ald1);

    // CSR build (dst-major)
    k_hist<<<(N_EDGES + 255) / 256, 256, 0, stream>>>(ei, deg);
    k_scan_part<<<NB_SCAN, 256, 0, stream>>>(deg, rowp, bsum);
    k_scan_block<<<1, 256, 0, stream>>>(bsum);
    k_scan_add<<<NB_SCAN, 256, 0, stream>>>(rowp, bsum, deg /*cursor*/);
    k_scatter<<<(N_EDGES + 255) / 256, 256, 0, stream>>>(ei, deg /*cursor*/, esrc);

    k_agg1_h<<<(N_NODES + 3) / 4, 256, 0, stream>>>(rowp, esrc, als1, ald1, xh1h, agg1);

    k_gemm2_mfma<<<(N_NODES + 63) / 64, 256, 0, stream>>>(agg1, b1, w2th, as2, ad2,
                                                          xh2h, als2, ald2);

    k_agg2_final<<<(N_NODES + 3) / 4, 256, 0, stream>>>(rowp, esrc, als2, ald2, xh2h,
                                                        b2, Wmu, bmu, Wlv, blv, out);
}

// Round 9
// 245.278 us; speedup vs baseline: 1.5231x; 1.0247x over previous
//
#include <hip/hip_runtime.h>
#include <hip/hip_fp16.h>

#define N_NODES 50000
#define N_EDGES 800000
#define IN_DIM  128
#define HID     64
#define HID2    32
#define HEADS   4
#define LATENT  32
#define NEG_SLOPE 0.2f

typedef _Float16 half8v __attribute__((ext_vector_type(8)));
typedef _Float16 half4v __attribute__((ext_vector_type(4)));
typedef float    float4v __attribute__((ext_vector_type(4)));

// ---------------- workspace layout (float offsets) ----------------
#define OFF_XH1H  ((size_t)0)            //  6,400,000 (half storage)
#define OFF_XH2H  ((size_t)0)            //  3,200,000 (overlay, xh1 dead)
#define OFF_ALS2  ((size_t)8000000)      //    200,000
#define OFF_ALD2  ((size_t)8200000)      //    200,000
#define OFF_AGG1  ((size_t)8400000)      //  3,200,000
#define OFF_ALS1  ((size_t)11600000)     //    200,000
#define OFF_ALD1  ((size_t)11800000)     //    200,000
// CSR (ints in float slots)
#define OFF_DEG   ((size_t)12000000)     //     50,000 (reused as scatter cursor)
#define OFF_ROW   ((size_t)12050000)     //     50,001
#define OFF_BSUM  ((size_t)12100004)     //        256
#define OFF_ESRC  ((size_t)12100260)     //    800,000
#define OFF_W1TH  ((size_t)12900260)     //     16,384 float slots (32768 halves)
#define OFF_W2TH  ((size_t)12916644)     //      4,096 float slots (8192 halves)

#define NB_SCAN ((N_NODES + 255) / 256)  // 196

__device__ __forceinline__ float lrelu(float v) {
    return v > 0.f ? v : NEG_SLOPE * v;
}

// ---------------- K0: weight fp16 transposes + deg zeroing (fused) ----------------
// blocks [0,160): cvt W1/W2; blocks [160, 160+NB_SCAN): zero deg
__global__ void k_prep(const float* __restrict__ W1, const float* __restrict__ W2,
                       __half* __restrict__ w1t, __half* __restrict__ w2t,
                       int* __restrict__ deg) {
    if (blockIdx.x < 160) {
        const int t = blockIdx.x * 256 + threadIdx.x;
        if (t < 32768) {
            const int k = t >> 8, n = t & 255;
            w1t[n * IN_DIM + k] = __float2half(W1[t]);
        } else {
            const int t2 = t - 32768;
            const int k = t2 >> 7, n = t2 & 127;
            w2t[n * HID + k] = __float2half(W2[t2]);
        }
    } else {
        const int i = (blockIdx.x - 160) * 256 + threadIdx.x;
        if (i < N_NODES) deg[i] = 0;
    }
}

// ---------------- K1: xh1h = half(x @ W1) via MFMA + fused als1/ald1 ----------------
// One block per 64-node row-block; x staged ONCE, 4 W-tiles looped in-block.
__global__ void k_gemm1_mfma(const float* __restrict__ x, const __half* __restrict__ w1t,
                             const float* __restrict__ as1, const float* __restrict__ ad1,
                             __half* __restrict__ xh1, float* __restrict__ als,
                             float* __restrict__ ald) {
    __shared__ _Float16 xsh[64][136];
    __shared__ _Float16 wsh[64][136];
    const int tid = threadIdx.x;
    const int m0 = blockIdx.x * 64;
#pragma unroll
    for (int i = 0; i < 8; i++) {
        const int f = tid + i * 256;
        const int r = f >> 5;
        const int k = (f & 31) * 4;
        const int gr = (m0 + r < N_NODES) ? (m0 + r) : (N_NODES - 1);
        const float4 xv = *(const float4*)(x + (size_t)gr * IN_DIM + k);
        half4v hv = { (_Float16)xv.x, (_Float16)xv.y, (_Float16)xv.z, (_Float16)xv.w };
        *(half4v*)&xsh[r][k] = hv;
    }
    const int w = tid >> 6, l = tid & 63;
    const int lr = l & 15;
    const int lk = (l >> 4) * 8;
    const int rbase = m0 + w * 16 + (l >> 4) * 4;
    for (int nb = 0; nb < 4; nb++) {
        const int n0 = nb * 64;
        __syncthreads();   // iter1: xsh ready-barrier pairing; iter>1: wsh readers done
#pragma unroll
        for (int i = 0; i < 4; i++) {
            const int u = tid + i * 256;
            const int r = u >> 4;
            const int k = (u & 15) * 8;
            *(half8v*)&wsh[r][k] = *(const half8v*)(w1t + (size_t)(n0 + r) * IN_DIM + k);
        }
        __syncthreads();
        float4v acc0 = {0.f,0.f,0.f,0.f}, acc1 = {0.f,0.f,0.f,0.f};
        float4v acc2 = {0.f,0.f,0.f,0.f}, acc3 = {0.f,0.f,0.f,0.f};
#pragma unroll
        for (int k0 = 0; k0 < IN_DIM; k0 += 32) {
            const half8v a  = *(const half8v*)&xsh[w * 16 + lr][k0 + lk];
            const half8v b0 = *(const half8v*)&wsh[ 0 + lr][k0 + lk];
            const half8v b1 = *(const half8v*)&wsh[16 + lr][k0 + lk];
            const half8v b2 = *(const half8v*)&wsh[32 + lr][k0 + lk];
            const half8v b3 = *(const half8v*)&wsh[48 + lr][k0 + lk];
            acc0 = __builtin_amdgcn_mfma_f32_16x16x32_f16(a, b0, acc0, 0, 0, 0);
            acc1 = __builtin_amdgcn_mfma_f32_16x16x32_f16(a, b1, acc1, 0, 0, 0);
            acc2 = __builtin_amdgcn_mfma_f32_16x16x32_f16(a, b2, acc2, 0, 0, 0);
            acc3 = __builtin_amdgcn_mfma_f32_16x16x32_f16(a, b3, acc3, 0, 0, 0);
        }
        const int cbase = n0 + lr;
#pragma unroll
        for (int r = 0; r < 4; r++) {
            const int node = rbase + r;
            if (node < N_NODES) {
                __half* p = xh1 + (size_t)node * (HEADS * HID) + cbase;
                p[0]  = __float2half(acc0[r]);
                p[16] = __float2half(acc1[r]);
                p[32] = __float2half(acc2[r]);
                p[48] = __float2half(acc3[r]);
            }
        }
        // fused attention logits for head h = nb
        const int h = nb;
        const float a0 = as1[(h << 6) + lr +  0], a1 = as1[(h << 6) + lr + 16];
        const float a2 = as1[(h << 6) + lr + 32], a3 = as1[(h << 6) + lr + 48];
        const float d0 = ad1[(h << 6) + lr +  0], d1 = ad1[(h << 6) + lr + 16];
        const float d2 = ad1[(h << 6) + lr + 32], d3 = ad1[(h << 6) + lr + 48];
#pragma unroll
        for (int r = 0; r < 4; r++) {
            float ps = acc0[r] * a0 + acc1[r] * a1 + acc2[r] * a2 + acc3[r] * a3;
            float pd = acc0[r] * d0 + acc1[r] * d1 + acc2[r] * d2 + acc3[r] * d3;
            ps += __shfl_xor(ps, 1); pd += __shfl_xor(pd, 1);
            ps += __shfl_xor(ps, 2); pd += __shfl_xor(pd, 2);
            ps += __shfl_xor(ps, 4); pd += __shfl_xor(pd, 4);
            ps += __shfl_xor(ps, 8); pd += __shfl_xor(pd, 8);
            if (lr == 0) {
                const int node = rbase + r;
                if (node < N_NODES) {
                    als[node * HEADS + h] = ps;
                    ald[node * HEADS + h] = pd;
                }
            }
        }
    }
}

// ---------------- CSR build ----------------
__global__ void k_hist(const int* __restrict__ ei, int* __restrict__ deg) {
    const int e = blockIdx.x * blockDim.x + threadIdx.x;
    if (e >= N_EDGES) return;
    atomicAdd(&deg[ei[N_EDGES + e]], 1);
}

__global__ void k_scan_part(const int* __restrict__ deg, int* __restrict__ row,
                            int* __restrict__ bsum) {
    __shared__ int sm[256];
    const int tid = threadIdx.x;
    const int i = blockIdx.x * 256 + tid;
    const int v = (i < N_NODES) ? deg[i] : 0;
    sm[tid] = v;
    __syncthreads();
    for (int off = 1; off < 256; off <<= 1) {
        int t = (tid >= off) ? sm[tid - off] : 0;
        __syncthreads();
        sm[tid] += t;
        __syncthreads();
    }
    if (i < N_NODES) row[i] = sm[tid] - v;
    if (tid == 255) bsum[blockIdx.x] = sm[255];
}

// scan_add with in-block computation of the block-prefix (replaces k_scan_block)
__global__ void k_scan_add(int* __restrict__ row, const int* __restrict__ bsum,
                           int* __restrict__ cur) {
    __shared__ int part[4];
    const int tid = threadIdx.x;
    const int bid = blockIdx.x;
    int v = (tid < bid) ? bsum[tid] : 0;   // bid < 196 < 256
    for (int off = 32; off; off >>= 1) v += __shfl_down(v, off);
    if ((tid & 63) == 0) part[tid >> 6] = v;
    __syncthreads();
    const int boff = part[0] + part[1] + part[2] + part[3];
    const int i = bid * 256 + tid;
    if (i == 0) row[N_NODES] = N_EDGES;
    if (i >= N_NODES) return;
    const int r = row[i] + boff;
    row[i] = r;
    cur[i] = r;
}

__global__ void k_scatter(const int* __restrict__ ei, int* __restrict__ cur,
                          int* __restrict__ esrc) {
    const int e = blockIdx.x * blockDim.x + threadIdx.x;
    if (e >= N_EDGES) return;
    const int s = ei[e], d = ei[N_EDGES + e];
    const int pos = atomicAdd(&cur[d], 1);
    esrc[pos] = s;
}

// ---------------- K3: layer-1 aggregation, wave/node, 8 gathers in flight ----------------
__global__ void k_agg1_h(const int* __restrict__ row, const int* __restrict__ esrc,
                         const float* __restrict__ als, const float* __restrict__ ald,
                         const __half* __restrict__ xh1, float* __restrict__ agg1) {
    const int d = blockIdx.x * 4 + (threadIdx.x >> 6);
    const int lane = threadIdx.x & 63;
    if (d >= N_NODES) return;
    const int hq = lane >> 4;
    const int he = lane & 3;
    const float adh = ald[d * 4 + he];
    const int start = row[d];
    const int total = row[d + 1] - start + 1;   // + self loop
    float acc0 = 0.f, acc1 = 0.f, acc2 = 0.f, acc3 = 0.f;
    float denp = 0.f;
    const size_t lby = (size_t)(lane << 3);
    for (int t0 = 0; t0 < total; t0 += 16) {
        int m = total - t0; if (m > 16) m = 16;
        const int slot = lane >> 2;
        float ev = 0.f; int s = d;
        if (slot < m) {
            const int t = t0 + slot;
            if (t > 0) s = esrc[start + t - 1];
            ev = expf(lrelu(als[s * 4 + he] + adh));
        }
        denp += ev;
        int j = 0;
        for (; j + 8 <= m; j += 8) {
            int ss[8]; float cc[8]; float2 rr[8];
#pragma unroll
            for (int u = 0; u < 8; u++) ss[u] = __shfl(s, (j + u) * 4);
#pragma unroll
            for (int u = 0; u < 8; u++)
                rr[u] = *(const float2*)((const char*)xh1 + ((size_t)ss[u] << 9) + lby);
#pragma unroll
            for (int u = 0; u < 8; u++) cc[u] = __shfl(ev, (j + u) * 4 + hq);
#pragma unroll
            for (int u = 0; u < 8; u++) {
                const float2 a = __half22float2(*(const __half2*)&rr[u].x);
                const float2 b = __half22float2(*(const __half2*)&rr[u].y);
                acc0 += cc[u] * a.x; acc1 += cc[u] * a.y;
                acc2 += cc[u] * b.x; acc3 += cc[u] * b.y;
            }
        }
        for (; j + 4 <= m; j += 4) {
            int ss[4]; float cc[4]; float2 rr[4];
#pragma unroll
            for (int u = 0; u < 4; u++) ss[u] = __shfl(s, (j + u) * 4);
#pragma unroll
            for (int u = 0; u < 4; u++)
                rr[u] = *(const float2*)((const char*)xh1 + ((size_t)ss[u] << 9) + lby);
#pragma unroll
            for (int u = 0; u < 4; u++) cc[u] = __shfl(ev, (j + u) * 4 + hq);
#pragma unroll
            for (int u = 0; u < 4; u++) {
                const float2 a = __half22float2(*(const __half2*)&rr[u].x);
                const float2 b = __half22float2(*(const __half2*)&rr[u].y);
                acc0 += cc[u] * a.x; acc1 += cc[u] * a.y;
                acc2 += cc[u] * b.x; acc3 += cc[u] * b.y;
            }
        }
        for (; j < m; j++) {
            const float cf = __shfl(ev, j * 4 + hq);
            const int sj   = __shfl(s, j * 4);
            const float2 raw = *(const float2*)((const char*)xh1 + ((size_t)sj << 9) + lby);
            const float2 a = __half22float2(*(const __half2*)&raw.x);
            const float2 b = __half22float2(*(const __half2*)&raw.y);
            acc0 += cf * a.x; acc1 += cf * a.y; acc2 += cf * b.x; acc3 += cf * b.y;
        }
    }
    denp += __shfl_xor(denp, 4);
    denp += __shfl_xor(denp, 8);
    denp += __shfl_xor(denp, 16);
    denp += __shfl_xor(denp, 32);
    const float deninv = 1.f / __shfl(denp, hq);
    acc0 *= deninv; acc1 *= deninv; acc2 *= deninv; acc3 *= deninv;
    acc0 += __shfl_xor(acc0, 16); acc0 += __shfl_xor(acc0, 32);
    acc1 += __shfl_xor(acc1, 16); acc1 += __shfl_xor(acc1, 32);
    acc2 += __shfl_xor(acc2, 16); acc2 += __shfl_xor(acc2, 32);
    acc3 += __shfl_xor(acc3, 16); acc3 += __shfl_xor(acc3, 32);
    if (lane < 16) {
        float4 st = { 0.25f * acc0, 0.25f * acc1, 0.25f * acc2, 0.25f * acc3 };
        *(float4*)(agg1 + (size_t)d * HID + lane * 4) = st;
    }
}

// ---------------- K5: xh2h = half(relu(agg1+b1) @ W2) via MFMA + fused als2/ald2 ----------------
__global__ void k_gemm2_mfma(const float* __restrict__ agg1, const float* __restrict__ b1,
                             const __half* __restrict__ w2t, const float* __restrict__ as2,
                             const float* __restrict__ ad2, __half* __restrict__ xh2,
                             float* __restrict__ als, float* __restrict__ ald) {
    __shared__ _Float16 ash[64][72];
    __shared__ _Float16 wsh[128][72];
    const int tid = threadIdx.x;
    const int m0 = blockIdx.x * 64;
#pragma unroll
    for (int i = 0; i < 4; i++) {
        const int f = tid + i * 256;
        const int r = f >> 4;
        const int k4 = (f & 15) * 4;
        const int gr = (m0 + r < N_NODES) ? (m0 + r) : (N_NODES - 1);
        float4 v = *(const float4*)(agg1 + (size_t)gr * HID + k4);
        v.x += b1[k4 + 0]; v.y += b1[k4 + 1];
        v.z += b1[k4 + 2]; v.w += b1[k4 + 3];
        v.x = v.x > 0.f ? v.x : 0.f;
        v.y = v.y > 0.f ? v.y : 0.f;
        v.z = v.z > 0.f ? v.z : 0.f;
        v.w = v.w > 0.f ? v.w : 0.f;
        half4v hv = { (_Float16)v.x, (_Float16)v.y, (_Float16)v.z, (_Float16)v.w };
        *(half4v*)&ash[r][k4] = hv;
    }
#pragma unroll
    for (int i = 0; i < 4; i++) {
        const int u = tid + i * 256;
        const int r = u >> 3;
        const int k = (u & 7) * 8;
        *(half8v*)&wsh[r][k] = *(const half8v*)(w2t + (size_t)r * HID + k);
    }
    __syncthreads();
    const int w = tid >> 6, l = tid & 63;
    const int lr = l & 15, lk = (l >> 4) * 8;
    float4v acc[8];
#pragma unroll
    for (int c = 0; c < 8; c++) acc[c] = (float4v){0.f, 0.f, 0.f, 0.f};
#pragma unroll
    for (int k0 = 0; k0 < HID; k0 += 32) {
        const half8v a = *(const half8v*)&ash[w * 16 + lr][k0 + lk];
#pragma unroll
        for (int c = 0; c < 8; c++) {
            const half8v b = *(const half8v*)&wsh[c * 16 + lr][k0 + lk];
            acc[c] = __builtin_amdgcn_mfma_f32_16x16x32_f16(a, b, acc[c], 0, 0, 0);
        }
    }
    const int rbase = m0 + w * 16 + (l >> 4) * 4;
#pragma unroll
    for (int r = 0; r < 4; r++) {
        const int node = rbase + r;
        if (node < N_NODES) {
            __half* p = xh2 + (size_t)node * (HEADS * HID2) + lr;
#pragma unroll
            for (int c = 0; c < 8; c++) p[c * 16] = __float2half(acc[c][r]);
        }
    }
    float av[8], dv[8];
#pragma unroll
    for (int c = 0; c < 8; c++) {
        const int hh = c >> 1, cih = lr + 16 * (c & 1);
        av[c] = as2[hh * HID2 + cih];
        dv[c] = ad2[hh * HID2 + cih];
    }
#pragma unroll
    for (int r = 0; r < 4; r++) {
        float ps0 = acc[0][r] * av[0] + acc[1][r] * av[1];
        float ps1 = acc[2][r] * av[2] + acc[3][r] * av[3];
        float ps2 = acc[4][r] * av[4] + acc[5][r] * av[5];
        float ps3 = acc[6][r] * av[6] + acc[7][r] * av[7];
        float pd0 = acc[0][r] * dv[0] + acc[1][r] * dv[1];
        float pd1 = acc[2][r] * dv[2] + acc[3][r] * dv[3];
        float pd2 = acc[4][r] * dv[4] + acc[5][r] * dv[5];
        float pd3 = acc[6][r] * dv[6] + acc[7][r] * dv[7];
#pragma unroll
        for (int off = 1; off <= 8; off <<= 1) {
            ps0 += __shfl_xor(ps0, off); ps1 += __shfl_xor(ps1, off);
            ps2 += __shfl_xor(ps2, off); ps3 += __shfl_xor(ps3, off);
            pd0 += __shfl_xor(pd0, off); pd1 += __shfl_xor(pd1, off);
            pd2 += __shfl_xor(pd2, off); pd3 += __shfl_xor(pd3, off);
        }
        if (lr == 0) {
            const int node = rbase + r;
            if (node < N_NODES) {
                float4 sv = { ps0, ps1, ps2, ps3 };
                float4 dvv = { pd0, pd1, pd2, pd3 };
                *(float4*)(als + (size_t)node * HEADS) = sv;
                *(float4*)(ald + (size_t)node * HEADS) = dvv;
            }
        }
    }
}

// ---------------- K7: layer-2 aggregation + fused final projections ----------------
__global__ void k_agg2_final(const int* __restrict__ row, const int* __restrict__ esrc,
                             const float* __restrict__ als, const float* __restrict__ ald,
                             const __half* __restrict__ xh2, const float* __restrict__ b2,
                             const float* __restrict__ Wmu, const float* __restrict__ bmu,
                             const float* __restrict__ Wlv, const float* __restrict__ blv,
                             float* __restrict__ out) {
    const int d = blockIdx.x * 4 + (threadIdx.x >> 6);
    const int lane = threadIdx.x & 63;
    if (d >= N_NODES) return;
    const int hq = lane >> 4;
    const int he = lane & 3;
    const float adh = ald[d * 4 + he];
    const int start = row[d];
    const int total = row[d + 1] - start + 1;   // + self loop
    float acc0 = 0.f, acc1 = 0.f;
    float denp = 0.f;
    const size_t lby = (size_t)(lane << 2);
    for (int t0 = 0; t0 < total; t0 += 16) {
        int m = total - t0; if (m > 16) m = 16;
        const int slot = lane >> 2;
        float ev = 0.f; int s = d;
        if (slot < m) {
            const int t = t0 + slot;
            if (t > 0) s = esrc[start + t - 1];
            ev = expf(lrelu(als[s * 4 + he] + adh));
        }
        denp += ev;
        int j = 0;
        for (; j + 8 <= m; j += 8) {
            int ss[8]; float cc[8]; __half2 rr[8];
#pragma unroll
            for (int u = 0; u < 8; u++) ss[u] = __shfl(s, (j + u) * 4);
#pragma unroll
            for (int u = 0; u < 8; u++)
                rr[u] = *(const __half2*)((const char*)xh2 + ((size_t)ss[u] << 8) + lby);
#pragma unroll
            for (int u = 0; u < 8; u++) cc[u] = __shfl(ev, (j + u) * 4 + hq);
#pragma unroll
            for (int u = 0; u < 8; u++) {
                const float2 xv = __half22float2(rr[u]);
                acc0 += cc[u] * xv.x; acc1 += cc[u] * xv.y;
            }
        }
        for (; j + 4 <= m; j += 4) {
            int ss[4]; float cc[4]; __half2 rr[4];
#pragma unroll
            for (int u = 0; u < 4; u++) ss[u] = __shfl(s, (j + u) * 4);
#pragma unroll
            for (int u = 0; u < 4; u++)
                rr[u] = *(const __half2*)((const char*)xh2 + ((size_t)ss[u] << 8) + lby);
#pragma unroll
            for (int u = 0; u < 4; u++) cc[u] = __shfl(ev, (j + u) * 4 + hq);
#pragma unroll
            for (int u = 0; u < 4; u++) {
                const float2 xv = __half22float2(rr[u]);
                acc0 += cc[u] * xv.x; acc1 += cc[u] * xv.y;
            }
        }
        for (; j < m; j++) {
            const float cf = __shfl(ev, j * 4 + hq);
            const int sj   = __shfl(s, j * 4);
            const __half2 hv = *(const __half2*)((const char*)xh2 + ((size_t)sj << 8) + lby);
            const float2 xv = __half22float2(hv);
            acc0 += cf * xv.x; acc1 += cf * xv.y;
        }
    }
    denp += __shfl_xor(denp, 4);
    denp += __shfl_xor(denp, 8);
    denp += __shfl_xor(denp, 16);
    denp += __shfl_xor(denp, 32);
    const float deninv = 1.f / __shfl(denp, hq);
    acc0 *= deninv; acc1 *= deninv;
    acc0 += __shfl_xor(acc0, 16); acc0 += __shfl_xor(acc0, 32);
    acc1 += __shfl_xor(acc1, 16); acc1 += __shfl_xor(acc1, 32);
    const int cp = lane & 15;
    float h0 = 0.25f * acc0 + b2[2 * cp];
    float h1 = 0.25f * acc1 + b2[2 * cp + 1];
    h0 = h0 > 0.f ? h0 : 0.f;
    h1 = h1 > 0.f ? h1 : 0.f;
    const int jj = lane & 31;
    const bool lv = lane >= 32;
    const float* Wp = lv ? Wlv : Wmu;
    const float* bp = lv ? blv : bmu;
    float o = bp[jj];
#pragma unroll
    for (int k = 0; k < 16; k++) {
        const float e0 = __shfl(h0, k);
        const float e1 = __shfl(h1, k);
        o += e0 * Wp[(2 * k) * LATENT + jj] + e1 * Wp[(2 * k + 1) * LATENT + jj];
    }
    out[(lv ? (size_t)N_NODES * LATENT : (size_t)0) + (size_t)d * LATENT + jj] = o;
}

extern "C" void kernel_launch(void* const* d_in, const int* in_sizes, int n_in,
                              void* d_out, int out_size, void* d_ws, size_t ws_size,
                              hipStream_t stream) {
    const float* x    = (const float*)d_in[0];
    const int*   ei   = (const int*)d_in[1];
    const float* W1   = (const float*)d_in[2];
    const float* as1  = (const float*)d_in[3];
    const float* ad1  = (const float*)d_in[4];
    const float* b1   = (const float*)d_in[5];
    const float* W2   = (const float*)d_in[6];
    const float* as2  = (const float*)d_in[7];
    const float* ad2  = (const float*)d_in[8];
    const float* b2   = (const float*)d_in[9];
    const float* Wmu  = (const float*)d_in[10];
    const float* bmu  = (const float*)d_in[11];
    const float* Wlv  = (const float*)d_in[12];
    const float* blv  = (const float*)d_in[13];
    float* out = (float*)d_out;
    float* ws  = (float*)d_ws;

    __half* xh1h = (__half*)(ws + OFF_XH1H);
    __half* xh2h = (__half*)(ws + OFF_XH2H);
    __half* w1th = (__half*)(ws + OFF_W1TH);
    __half* w2th = (__half*)(ws + OFF_W2TH);
    float* als1 = ws + OFF_ALS1;
    float* ald1 = ws + OFF_ALD1;
    float* agg1 = ws + OFF_AGG1;
    float* als2 = ws + OFF_ALS2;
    float* ald2 = ws + OFF_ALD2;
    int* deg  = (int*)(ws + OFF_DEG);
    int* rowp = (int*)(ws + OFF_ROW);
    int* bsum = (int*)(ws + OFF_BSUM);
    int* esrc = (int*)(ws + OFF_ESRC);

    k_prep<<<160 + NB_SCAN, 256, 0, stream>>>(W1, W2, w1th, w2th, deg);
    k_gemm1_mfma<<<(N_NODES + 63) / 64, 256, 0, stream>>>(x, w1th, as1, ad1,
                                                          xh1h, als1, ald1);

    // CSR build (dst-major)
    k_hist<<<(N_EDGES + 255) / 256, 256, 0, stream>>>(ei, deg);
    k_scan_part<<<NB_SCAN, 256, 0, stream>>>(deg, rowp, bsum);
    k_scan_add<<<NB_SCAN, 256, 0, stream>>>(rowp, bsum, deg /*cursor*/);
    k_scatter<<<(N_EDGES + 255) / 256, 256, 0, stream>>>(ei, deg /*cursor*/, esrc);

    k_agg1_h<<<(N_NODES + 3) / 4, 256, 0, stream>>>(rowp, esrc, als1, ald1, xh1h, agg1);

    k_gemm2_mfma<<<(N_NODES + 63) / 64, 256, 0, stream>>>(agg1, b1, w2th, as2, ad2,
                                                          xh2h, als2, ald2);

    k_agg2_final<<<(N_NODES + 3) / 4, 256, 0, stream>>>(rowp, esrc, als2, ald2, xh2h,
                                                        b2, Wmu, bmu, Wlv, blv, out);
}

// Round 10
// 212.348 us; speedup vs baseline: 1.7593x; 1.1551x over previous
//
#include <hip/hip_runtime.h>
#include <hip/hip_fp16.h>

#define N_NODES 50000
#define N_EDGES 800000
#define IN_DIM  128
#define HID     64
#define HID2    32
#define HEADS   4
#define LATENT  32
#define NEG_SLOPE 0.2f
#define BINCAP  64   // max in-degree capacity; P(exceed) ~ e^-41 for Binom(800k,1/50k)

typedef _Float16 half8v __attribute__((ext_vector_type(8)));
typedef _Float16 half4v __attribute__((ext_vector_type(4)));
typedef float    float4v __attribute__((ext_vector_type(4)));

// ---------------- workspace layout (float offsets) ----------------
#define OFF_XH1H  ((size_t)0)            //  6,400,000 (half storage)
#define OFF_XH2H  ((size_t)0)            //  3,200,000 (overlay, xh1 dead)
#define OFF_ALS2  ((size_t)8000000)      //    200,000
#define OFF_ALD2  ((size_t)8200000)      //    200,000
#define OFF_AGG1  ((size_t)8400000)      //  3,200,000
#define OFF_ALS1  ((size_t)11600000)     //    200,000
#define OFF_ALD1  ((size_t)11800000)     //    200,000
#define OFF_CUR   ((size_t)12000000)     //     50,000 ints (cursor == degree)
#define OFF_ESRC  ((size_t)12050000)     //  3,200,000 ints (50k x 64 bins)
#define OFF_W1TH  ((size_t)15250000)     //     16,384 float slots (32768 halves)
#define OFF_W2TH  ((size_t)15266384)     //      4,096 float slots (8192 halves)
// total 15,270,480 floats = 61.1 MB

#define NB_ZERO ((N_NODES + 255) / 256)  // 196

__device__ __forceinline__ float lrelu(float v) {
    return v > 0.f ? v : NEG_SLOPE * v;
}

// ---------------- K0: weight fp16 transposes + cursor zeroing (fused) ----------------
__global__ void k_prep(const float* __restrict__ W1, const float* __restrict__ W2,
                       __half* __restrict__ w1t, __half* __restrict__ w2t,
                       int* __restrict__ cur) {
    if (blockIdx.x < 160) {
        const int t = blockIdx.x * 256 + threadIdx.x;
        if (t < 32768) {
            const int k = t >> 8, n = t & 255;
            w1t[n * IN_DIM + k] = __float2half(W1[t]);
        } else {
            const int t2 = t - 32768;
            const int k = t2 >> 7, n = t2 & 127;
            w2t[n * HID + k] = __float2half(W2[t2]);
        }
    } else {
        const int i = (blockIdx.x - 160) * 256 + threadIdx.x;
        if (i < N_NODES) cur[i] = 0;
    }
}

// ---------------- K1: xh1h = half(x @ W1) MFMA + fused als1/ald1 + edge binning ----------------
// One block per 64-node row-block; x staged once, 4 W-tiles looped in-block.
// Tail: each block bins 1024 edges (pos = atomicAdd(cur[dst]); esrc[dst*64+pos] = src).
__global__ void k_gemm1_mfma(const float* __restrict__ x, const __half* __restrict__ w1t,
                             const float* __restrict__ as1, const float* __restrict__ ad1,
                             __half* __restrict__ xh1, float* __restrict__ als,
                             float* __restrict__ ald, const int* __restrict__ ei,
                             int* __restrict__ cur, int* __restrict__ esrc) {
    __shared__ _Float16 xsh[64][136];
    __shared__ _Float16 wsh[64][136];
    const int tid = threadIdx.x;
    const int m0 = blockIdx.x * 64;
#pragma unroll
    for (int i = 0; i < 8; i++) {
        const int f = tid + i * 256;
        const int r = f >> 5;
        const int k = (f & 31) * 4;
        const int gr = (m0 + r < N_NODES) ? (m0 + r) : (N_NODES - 1);
        const float4 xv = *(const float4*)(x + (size_t)gr * IN_DIM + k);
        half4v hv = { (_Float16)xv.x, (_Float16)xv.y, (_Float16)xv.z, (_Float16)xv.w };
        *(half4v*)&xsh[r][k] = hv;
    }
    const int w = tid >> 6, l = tid & 63;
    const int lr = l & 15;
    const int lk = (l >> 4) * 8;
    const int rbase = m0 + w * 16 + (l >> 4) * 4;
    for (int nb = 0; nb < 4; nb++) {
        const int n0 = nb * 64;
        __syncthreads();
#pragma unroll
        for (int i = 0; i < 4; i++) {
            const int u = tid + i * 256;
            const int r = u >> 4;
            const int k = (u & 15) * 8;
            *(half8v*)&wsh[r][k] = *(const half8v*)(w1t + (size_t)(n0 + r) * IN_DIM + k);
        }
        __syncthreads();
        float4v acc0 = {0.f,0.f,0.f,0.f}, acc1 = {0.f,0.f,0.f,0.f};
        float4v acc2 = {0.f,0.f,0.f,0.f}, acc3 = {0.f,0.f,0.f,0.f};
#pragma unroll
        for (int k0 = 0; k0 < IN_DIM; k0 += 32) {
            const half8v a  = *(const half8v*)&xsh[w * 16 + lr][k0 + lk];
            const half8v b0 = *(const half8v*)&wsh[ 0 + lr][k0 + lk];
            const half8v b1 = *(const half8v*)&wsh[16 + lr][k0 + lk];
            const half8v b2 = *(const half8v*)&wsh[32 + lr][k0 + lk];
            const half8v b3 = *(const half8v*)&wsh[48 + lr][k0 + lk];
            acc0 = __builtin_amdgcn_mfma_f32_16x16x32_f16(a, b0, acc0, 0, 0, 0);
            acc1 = __builtin_amdgcn_mfma_f32_16x16x32_f16(a, b1, acc1, 0, 0, 0);
            acc2 = __builtin_amdgcn_mfma_f32_16x16x32_f16(a, b2, acc2, 0, 0, 0);
            acc3 = __builtin_amdgcn_mfma_f32_16x16x32_f16(a, b3, acc3, 0, 0, 0);
        }
        const int cbase = n0 + lr;
#pragma unroll
        for (int r = 0; r < 4; r++) {
            const int node = rbase + r;
            if (node < N_NODES) {
                __half* p = xh1 + (size_t)node * (HEADS * HID) + cbase;
                p[0]  = __float2half(acc0[r]);
                p[16] = __float2half(acc1[r]);
                p[32] = __float2half(acc2[r]);
                p[48] = __float2half(acc3[r]);
            }
        }
        const int h = nb;
        const float a0 = as1[(h << 6) + lr +  0], a1 = as1[(h << 6) + lr + 16];
        const float a2 = as1[(h << 6) + lr + 32], a3 = as1[(h << 6) + lr + 48];
        const float d0 = ad1[(h << 6) + lr +  0], d1 = ad1[(h << 6) + lr + 16];
        const float d2 = ad1[(h << 6) + lr + 32], d3 = ad1[(h << 6) + lr + 48];
#pragma unroll
        for (int r = 0; r < 4; r++) {
            float ps = acc0[r] * a0 + acc1[r] * a1 + acc2[r] * a2 + acc3[r] * a3;
            float pd = acc0[r] * d0 + acc1[r] * d1 + acc2[r] * d2 + acc3[r] * d3;
            ps += __shfl_xor(ps, 1); pd += __shfl_xor(pd, 1);
            ps += __shfl_xor(ps, 2); pd += __shfl_xor(pd, 2);
            ps += __shfl_xor(ps, 4); pd += __shfl_xor(pd, 4);
            ps += __shfl_xor(ps, 8); pd += __shfl_xor(pd, 8);
            if (lr == 0) {
                const int node = rbase + r;
                if (node < N_NODES) {
                    als[node * HEADS + h] = ps;
                    ald[node * HEADS + h] = pd;
                }
            }
        }
    }
    // ---- edge binning tail: 1024 edges per block ----
#pragma unroll
    for (int q = 0; q < 4; q++) {
        const int e = blockIdx.x * 1024 + q * 256 + tid;
        if (e < N_EDGES) {
            const int s = ei[e], dd = ei[N_EDGES + e];
            const int pos = atomicAdd(&cur[dd], 1);
            esrc[(dd << 6) + pos] = s;
        }
    }
}

// ---------------- K3: layer-1 aggregation, wave/node, 8 gathers in flight ----------------
__global__ void k_agg1_h(const int* __restrict__ cnt, const int* __restrict__ esrc,
                         const float* __restrict__ als, const float* __restrict__ ald,
                         const __half* __restrict__ xh1, float* __restrict__ agg1) {
    const int d = blockIdx.x * 4 + (threadIdx.x >> 6);
    const int lane = threadIdx.x & 63;
    if (d >= N_NODES) return;
    const int hq = lane >> 4;
    const int he = lane & 3;
    const float adh = ald[d * 4 + he];
    const int base = d << 6;
    const int total = cnt[d] + 1;   // + self loop
    float acc0 = 0.f, acc1 = 0.f, acc2 = 0.f, acc3 = 0.f;
    float denp = 0.f;
    const size_t lby = (size_t)(lane << 3);
    for (int t0 = 0; t0 < total; t0 += 16) {
        int m = total - t0; if (m > 16) m = 16;
        const int slot = lane >> 2;
        float ev = 0.f; int s = d;
        if (slot < m) {
            const int t = t0 + slot;
            if (t > 0) s = esrc[base + t - 1];
            ev = expf(lrelu(als[s * 4 + he] + adh));
        }
        denp += ev;
        int j = 0;
        for (; j + 8 <= m; j += 8) {
            int ss[8]; float cc[8]; float2 rr[8];
#pragma unroll
            for (int u = 0; u < 8; u++) ss[u] = __shfl(s, (j + u) * 4);
#pragma unroll
            for (int u = 0; u < 8; u++)
                rr[u] = *(const float2*)((const char*)xh1 + ((size_t)ss[u] << 9) + lby);
#pragma unroll
            for (int u = 0; u < 8; u++) cc[u] = __shfl(ev, (j + u) * 4 + hq);
#pragma unroll
            for (int u = 0; u < 8; u++) {
                const float2 a = __half22float2(*(const __half2*)&rr[u].x);
                const float2 b = __half22float2(*(const __half2*)&rr[u].y);
                acc0 += cc[u] * a.x; acc1 += cc[u] * a.y;
                acc2 += cc[u] * b.x; acc3 += cc[u] * b.y;
            }
        }
        for (; j + 4 <= m; j += 4) {
            int ss[4]; float cc[4]; float2 rr[4];
#pragma unroll
            for (int u = 0; u < 4; u++) ss[u] = __shfl(s, (j + u) * 4);
#pragma unroll
            for (int u = 0; u < 4; u++)
                rr[u] = *(const float2*)((const char*)xh1 + ((size_t)ss[u] << 9) + lby);
#pragma unroll
            for (int u = 0; u < 4; u++) cc[u] = __shfl(ev, (j + u) * 4 + hq);
#pragma unroll
            for (int u = 0; u < 4; u++) {
                const float2 a = __half22float2(*(const __half2*)&rr[u].x);
                const float2 b = __half22float2(*(const __half2*)&rr[u].y);
                acc0 += cc[u] * a.x; acc1 += cc[u] * a.y;
                acc2 += cc[u] * b.x; acc3 += cc[u] * b.y;
            }
        }
        for (; j < m; j++) {
            const float cf = __shfl(ev, j * 4 + hq);
            const int sj   = __shfl(s, j * 4);
            const float2 raw = *(const float2*)((const char*)xh1 + ((size_t)sj << 9) + lby);
            const float2 a = __half22float2(*(const __half2*)&raw.x);
            const float2 b = __half22float2(*(const __half2*)&raw.y);
            acc0 += cf * a.x; acc1 += cf * a.y; acc2 += cf * b.x; acc3 += cf * b.y;
        }
    }
    denp += __shfl_xor(denp, 4);
    denp += __shfl_xor(denp, 8);
    denp += __shfl_xor(denp, 16);
    denp += __shfl_xor(denp, 32);
    const float deninv = 1.f / __shfl(denp, hq);
    acc0 *= deninv; acc1 *= deninv; acc2 *= deninv; acc3 *= deninv;
    acc0 += __shfl_xor(acc0, 16); acc0 += __shfl_xor(acc0, 32);
    acc1 += __shfl_xor(acc1, 16); acc1 += __shfl_xor(acc1, 32);
    acc2 += __shfl_xor(acc2, 16); acc2 += __shfl_xor(acc2, 32);
    acc3 += __shfl_xor(acc3, 16); acc3 += __shfl_xor(acc3, 32);
    if (lane < 16) {
        float4 st = { 0.25f * acc0, 0.25f * acc1, 0.25f * acc2, 0.25f * acc3 };
        *(float4*)(agg1 + (size_t)d * HID + lane * 4) = st;
    }
}

// ---------------- K5: xh2h = half(relu(agg1+b1) @ W2) via MFMA + fused als2/ald2 ----------------
__global__ void k_gemm2_mfma(const float* __restrict__ agg1, const float* __restrict__ b1,
                             const __half* __restrict__ w2t, const float* __restrict__ as2,
                             const float* __restrict__ ad2, __half* __restrict__ xh2,
                             float* __restrict__ als, float* __restrict__ ald) {
    __shared__ _Float16 ash[64][72];
    __shared__ _Float16 wsh[128][72];
    const int tid = threadIdx.x;
    const int m0 = blockIdx.x * 64;
#pragma unroll
    for (int i = 0; i < 4; i++) {
        const int f = tid + i * 256;
        const int r = f >> 4;
        const int k4 = (f & 15) * 4;
        const int gr = (m0 + r < N_NODES) ? (m0 + r) : (N_NODES - 1);
        float4 v = *(const float4*)(agg1 + (size_t)gr * HID + k4);
        v.x += b1[k4 + 0]; v.y += b1[k4 + 1];
        v.z += b1[k4 + 2]; v.w += b1[k4 + 3];
        v.x = v.x > 0.f ? v.x : 0.f;
        v.y = v.y > 0.f ? v.y : 0.f;
        v.z = v.z > 0.f ? v.z : 0.f;
        v.w = v.w > 0.f ? v.w : 0.f;
        half4v hv = { (_Float16)v.x, (_Float16)v.y, (_Float16)v.z, (_Float16)v.w };
        *(half4v*)&ash[r][k4] = hv;
    }
#pragma unroll
    for (int i = 0; i < 4; i++) {
        const int u = tid + i * 256;
        const int r = u >> 3;
        const int k = (u & 7) * 8;
        *(half8v*)&wsh[r][k] = *(const half8v*)(w2t + (size_t)r * HID + k);
    }
    __syncthreads();
    const int w = tid >> 6, l = tid & 63;
    const int lr = l & 15, lk = (l >> 4) * 8;
    float4v acc[8];
#pragma unroll
    for (int c = 0; c < 8; c++) acc[c] = (float4v){0.f, 0.f, 0.f, 0.f};
#pragma unroll
    for (int k0 = 0; k0 < HID; k0 += 32) {
        const half8v a = *(const half8v*)&ash[w * 16 + lr][k0 + lk];
#pragma unroll
        for (int c = 0; c < 8; c++) {
            const half8v b = *(const half8v*)&wsh[c * 16 + lr][k0 + lk];
            acc[c] = __builtin_amdgcn_mfma_f32_16x16x32_f16(a, b, acc[c], 0, 0, 0);
        }
    }
    const int rbase = m0 + w * 16 + (l >> 4) * 4;
#pragma unroll
    for (int r = 0; r < 4; r++) {
        const int node = rbase + r;
        if (node < N_NODES) {
            __half* p = xh2 + (size_t)node * (HEADS * HID2) + lr;
#pragma unroll
            for (int c = 0; c < 8; c++) p[c * 16] = __float2half(acc[c][r]);
        }
    }
    float av[8], dv[8];
#pragma unroll
    for (int c = 0; c < 8; c++) {
        const int hh = c >> 1, cih = lr + 16 * (c & 1);
        av[c] = as2[hh * HID2 + cih];
        dv[c] = ad2[hh * HID2 + cih];
    }
#pragma unroll
    for (int r = 0; r < 4; r++) {
        float ps0 = acc[0][r] * av[0] + acc[1][r] * av[1];
        float ps1 = acc[2][r] * av[2] + acc[3][r] * av[3];
        float ps2 = acc[4][r] * av[4] + acc[5][r] * av[5];
        float ps3 = acc[6][r] * av[6] + acc[7][r] * av[7];
        float pd0 = acc[0][r] * dv[0] + acc[1][r] * dv[1];
        float pd1 = acc[2][r] * dv[2] + acc[3][r] * dv[3];
        float pd2 = acc[4][r] * dv[4] + acc[5][r] * dv[5];
        float pd3 = acc[6][r] * dv[6] + acc[7][r] * dv[7];
#pragma unroll
        for (int off = 1; off <= 8; off <<= 1) {
            ps0 += __shfl_xor(ps0, off); ps1 += __shfl_xor(ps1, off);
            ps2 += __shfl_xor(ps2, off); ps3 += __shfl_xor(ps3, off);
            pd0 += __shfl_xor(pd0, off); pd1 += __shfl_xor(pd1, off);
            pd2 += __shfl_xor(pd2, off); pd3 += __shfl_xor(pd3, off);
        }
        if (lr == 0) {
            const int node = rbase + r;
            if (node < N_NODES) {
                float4 sv = { ps0, ps1, ps2, ps3 };
                float4 dvv = { pd0, pd1, pd2, pd3 };
                *(float4*)(als + (size_t)node * HEADS) = sv;
                *(float4*)(ald + (size_t)node * HEADS) = dvv;
            }
        }
    }
}

// ---------------- K7: layer-2 aggregation + fused final projections ----------------
__global__ void k_agg2_final(const int* __restrict__ cnt, const int* __restrict__ esrc,
                             const float* __restrict__ als, const float* __restrict__ ald,
                             const __half* __restrict__ xh2, const float* __restrict__ b2,
                             const float* __restrict__ Wmu, const float* __restrict__ bmu,
                             const float* __restrict__ Wlv, const float* __restrict__ blv,
                             float* __restrict__ out) {
    const int d = blockIdx.x * 4 + (threadIdx.x >> 6);
    const int lane = threadIdx.x & 63;
    if (d >= N_NODES) return;
    const int hq = lane >> 4;
    const int he = lane & 3;
    const float adh = ald[d * 4 + he];
    const int base = d << 6;
    const int total = cnt[d] + 1;   // + self loop
    float acc0 = 0.f, acc1 = 0.f;
    float denp = 0.f;
    const size_t lby = (size_t)(lane << 2);
    for (int t0 = 0; t0 < total; t0 += 16) {
        int m = total - t0; if (m > 16) m = 16;
        const int slot = lane >> 2;
        float ev = 0.f; int s = d;
        if (slot < m) {
            const int t = t0 + slot;
            if (t > 0) s = esrc[base + t - 1];
            ev = expf(lrelu(als[s * 4 + he] + adh));
        }
        denp += ev;
        int j = 0;
        for (; j + 8 <= m; j += 8) {
            int ss[8]; float cc[8]; __half2 rr[8];
#pragma unroll
            for (int u = 0; u < 8; u++) ss[u] = __shfl(s, (j + u) * 4);
#pragma unroll
            for (int u = 0; u < 8; u++)
                rr[u] = *(const __half2*)((const char*)xh2 + ((size_t)ss[u] << 8) + lby);
#pragma unroll
            for (int u = 0; u < 8; u++) cc[u] = __shfl(ev, (j + u) * 4 + hq);
#pragma unroll
            for (int u = 0; u < 8; u++) {
                const float2 xv = __half22float2(rr[u]);
                acc0 += cc[u] * xv.x; acc1 += cc[u] * xv.y;
            }
        }
        for (; j + 4 <= m; j += 4) {
            int ss[4]; float cc[4]; __half2 rr[4];
#pragma unroll
            for (int u = 0; u < 4; u++) ss[u] = __shfl(s, (j + u) * 4);
#pragma unroll
            for (int u = 0; u < 4; u++)
                rr[u] = *(const __half2*)((const char*)xh2 + ((size_t)ss[u] << 8) + lby);
#pragma unroll
            for (int u = 0; u < 4; u++) cc[u] = __shfl(ev, (j + u) * 4 + hq);
#pragma unroll
            for (int u = 0; u < 4; u++) {
                const float2 xv = __half22float2(rr[u]);
                acc0 += cc[u] * xv.x; acc1 += cc[u] * xv.y;
            }
        }
        for (; j < m; j++) {
            const float cf = __shfl(ev, j * 4 + hq);
            const int sj   = __shfl(s, j * 4);
            const __half2 hv = *(const __half2*)((const char*)xh2 + ((size_t)sj << 8) + lby);
            const float2 xv = __half22float2(hv);
            acc0 += cf * xv.x; acc1 += cf * xv.y;
        }
    }
    denp += __shfl_xor(denp, 4);
    denp += __shfl_xor(denp, 8);
    denp += __shfl_xor(denp, 16);
    denp += __shfl_xor(denp, 32);
    const float deninv = 1.f / __shfl(denp, hq);
    acc0 *= deninv; acc1 *= deninv;
    acc0 += __shfl_xor(acc0, 16); acc0 += __shfl_xor(acc0, 32);
    acc1 += __shfl_xor(acc1, 16); acc1 += __shfl_xor(acc1, 32);
    const int cp = lane & 15;
    float h0 = 0.25f * acc0 + b2[2 * cp];
    float h1 = 0.25f * acc1 + b2[2 * cp + 1];
    h0 = h0 > 0.f ? h0 : 0.f;
    h1 = h1 > 0.f ? h1 : 0.f;
    const int jj = lane & 31;
    const bool lv = lane >= 32;
    const float* Wp = lv ? Wlv : Wmu;
    const float* bp = lv ? blv : bmu;
    float o = bp[jj];
#pragma unroll
    for (int k = 0; k < 16; k++) {
        const float e0 = __shfl(h0, k);
        const float e1 = __shfl(h1, k);
        o += e0 * Wp[(2 * k) * LATENT + jj] + e1 * Wp[(2 * k + 1) * LATENT + jj];
    }
    out[(lv ? (size_t)N_NODES * LATENT : (size_t)0) + (size_t)d * LATENT + jj] = o;
}

extern "C" void kernel_launch(void* const* d_in, const int* in_sizes, int n_in,
                              void* d_out, int out_size, void* d_ws, size_t ws_size,
                              hipStream_t stream) {
    const float* x    = (const float*)d_in[0];
    const int*   ei   = (const int*)d_in[1];
    const float* W1   = (const float*)d_in[2];
    const float* as1  = (const float*)d_in[3];
    const float* ad1  = (const float*)d_in[4];
    const float* b1   = (const float*)d_in[5];
    const float* W2   = (const float*)d_in[6];
    const float* as2  = (const float*)d_in[7];
    const float* ad2  = (const float*)d_in[8];
    const float* b2   = (const float*)d_in[9];
    const float* Wmu  = (const float*)d_in[10];
    const float* bmu  = (const float*)d_in[11];
    const float* Wlv  = (const float*)d_in[12];
    const float* blv  = (const float*)d_in[13];
    float* out = (float*)d_out;
    float* ws  = (float*)d_ws;

    __half* xh1h = (__half*)(ws + OFF_XH1H);
    __half* xh2h = (__half*)(ws + OFF_XH2H);
    __half* w1th = (__half*)(ws + OFF_W1TH);
    __half* w2th = (__half*)(ws + OFF_W2TH);
    float* als1 = ws + OFF_ALS1;
    float* ald1 = ws + OFF_ALD1;
    float* agg1 = ws + OFF_AGG1;
    float* als2 = ws + OFF_ALS2;
    float* ald2 = ws + OFF_ALD2;
    int* cur  = (int*)(ws + OFF_CUR);
    int* esrc = (int*)(ws + OFF_ESRC);

    k_prep<<<160 + NB_ZERO, 256, 0, stream>>>(W1, W2, w1th, w2th, cur);

    k_gemm1_mfma<<<(N_NODES + 63) / 64, 256, 0, stream>>>(x, w1th, as1, ad1, xh1h,
                                                          als1, ald1, ei, cur, esrc);

    k_agg1_h<<<(N_NODES + 3) / 4, 256, 0, stream>>>(cur, esrc, als1, ald1, xh1h, agg1);

    k_gemm2_mfma<<<(N_NODES + 63) / 64, 256, 0, stream>>>(agg1, b1, w2th, as2, ad2,
                                                          xh2h, als2, ald2);

    k_agg2_final<<<(N_NODES + 3) / 4, 256, 0, stream>>>(cur, esrc, als2, ald2, xh2h,
                                                        b2, Wmu, bmu, Wlv, blv, out);
}

// Round 11
// 202.499 us; speedup vs baseline: 1.8449x; 1.0486x over previous
//
#include <hip/hip_runtime.h>
#include <hip/hip_fp16.h>

#define N_NODES 50000
#define N_EDGES 800000
#define IN_DIM  128
#define HID     64
#define HID2    32
#define HEADS   4
#define LATENT  32
#define NEG_SLOPE 0.2f
#define BINCAP  64   // max in-degree capacity; max deg ~38 for Binom(800k,1/50k)

#define GB1   ((N_NODES + 63) / 64)      // 782 gemm1 blocks
#define NBIN  ((N_EDGES + 255) / 256)    // 3125 binning blocks

typedef _Float16 half8v __attribute__((ext_vector_type(8)));
typedef _Float16 half4v __attribute__((ext_vector_type(4)));
typedef float    float4v __attribute__((ext_vector_type(4)));

// ---------------- workspace layout (float offsets) ----------------
#define OFF_XH1H  ((size_t)0)            //  6,400,000 (half storage)
#define OFF_XH2H  ((size_t)0)            //  3,200,000 (overlay, xh1 dead)
#define OFF_ALS2  ((size_t)8000000)      //    200,000
#define OFF_ALD2  ((size_t)8200000)      //    200,000
#define OFF_AGG1  ((size_t)8400000)      //  3,200,000
#define OFF_ALS1  ((size_t)11600000)     //    200,000
#define OFF_ALD1  ((size_t)11800000)     //    200,000
#define OFF_CUR   ((size_t)12000000)     //     50,000 ints (cursor == degree)
#define OFF_ESRC  ((size_t)12050000)     //  3,200,000 ints (50k x 64 bins)
#define OFF_W1TH  ((size_t)15250000)     //     16,384 float slots (32768 halves)
#define OFF_W2TH  ((size_t)15266384)     //      4,096 float slots (8192 halves)
// total 15,270,480 floats = 61.1 MB

#define NB_ZERO ((N_NODES + 255) / 256)  // 196

__device__ __forceinline__ float lrelu(float v) {
    return v > 0.f ? v : NEG_SLOPE * v;
}

// ---------------- K0: weight fp16 transposes + cursor zeroing (fused) ----------------
__global__ void k_prep(const float* __restrict__ W1, const float* __restrict__ W2,
                       __half* __restrict__ w1t, __half* __restrict__ w2t,
                       int* __restrict__ cur) {
    if (blockIdx.x < 160) {
        const int t = blockIdx.x * 256 + threadIdx.x;
        if (t < 32768) {
            const int k = t >> 8, n = t & 255;
            w1t[n * IN_DIM + k] = __float2half(W1[t]);
        } else {
            const int t2 = t - 32768;
            const int k = t2 >> 7, n = t2 & 127;
            w2t[n * HID + k] = __float2half(W2[t2]);
        }
    } else {
        const int i = (blockIdx.x - 160) * 256 + threadIdx.x;
        if (i < N_NODES) cur[i] = 0;
    }
}

// ---------------- K1 (hybrid dispatch):
//   blocks [0, GB1):      xh1h = half(x @ W1) MFMA + fused als1/ald1
//   blocks [GB1, GB1+NBIN): edge binning, 1 edge/thread (overlaps the GEMM)
__global__ void k_gemm1_mfma(const float* __restrict__ x, const __half* __restrict__ w1t,
                             const float* __restrict__ as1, const float* __restrict__ ad1,
                             __half* __restrict__ xh1, float* __restrict__ als,
                             float* __restrict__ ald, const int* __restrict__ ei,
                             int* __restrict__ cur, int* __restrict__ esrc) {
    const int tid = threadIdx.x;
    if (blockIdx.x >= GB1) {
        // ---- edge binning blocks: no LDS, pure memory; co-resident with GEMM ----
        const int e = (blockIdx.x - GB1) * 256 + tid;
        if (e < N_EDGES) {
            const int s = ei[e], dd = ei[N_EDGES + e];
            const int pos = atomicAdd(&cur[dd], 1);
            if (pos < BINCAP)
                __builtin_nontemporal_store(s, &esrc[(dd << 6) + pos]);
        }
        return;
    }
    __shared__ _Float16 xsh[64][136];
    __shared__ _Float16 wsh[64][136];
    const int m0 = blockIdx.x * 64;
#pragma unroll
    for (int i = 0; i < 8; i++) {
        const int f = tid + i * 256;
        const int r = f >> 5;
        const int k = (f & 31) * 4;
        const int gr = (m0 + r < N_NODES) ? (m0 + r) : (N_NODES - 1);
        const float4 xv = *(const float4*)(x + (size_t)gr * IN_DIM + k);
        half4v hv = { (_Float16)xv.x, (_Float16)xv.y, (_Float16)xv.z, (_Float16)xv.w };
        *(half4v*)&xsh[r][k] = hv;
    }
    const int w = tid >> 6, l = tid & 63;
    const int lr = l & 15;
    const int lk = (l >> 4) * 8;
    const int rbase = m0 + w * 16 + (l >> 4) * 4;
    for (int nb = 0; nb < 4; nb++) {
        const int n0 = nb * 64;
        __syncthreads();
#pragma unroll
        for (int i = 0; i < 4; i++) {
            const int u = tid + i * 256;
            const int r = u >> 4;
            const int k = (u & 15) * 8;
            *(half8v*)&wsh[r][k] = *(const half8v*)(w1t + (size_t)(n0 + r) * IN_DIM + k);
        }
        __syncthreads();
        float4v acc0 = {0.f,0.f,0.f,0.f}, acc1 = {0.f,0.f,0.f,0.f};
        float4v acc2 = {0.f,0.f,0.f,0.f}, acc3 = {0.f,0.f,0.f,0.f};
#pragma unroll
        for (int k0 = 0; k0 < IN_DIM; k0 += 32) {
            const half8v a  = *(const half8v*)&xsh[w * 16 + lr][k0 + lk];
            const half8v b0 = *(const half8v*)&wsh[ 0 + lr][k0 + lk];
            const half8v b1 = *(const half8v*)&wsh[16 + lr][k0 + lk];
            const half8v b2 = *(const half8v*)&wsh[32 + lr][k0 + lk];
            const half8v b3 = *(const half8v*)&wsh[48 + lr][k0 + lk];
            acc0 = __builtin_amdgcn_mfma_f32_16x16x32_f16(a, b0, acc0, 0, 0, 0);
            acc1 = __builtin_amdgcn_mfma_f32_16x16x32_f16(a, b1, acc1, 0, 0, 0);
            acc2 = __builtin_amdgcn_mfma_f32_16x16x32_f16(a, b2, acc2, 0, 0, 0);
            acc3 = __builtin_amdgcn_mfma_f32_16x16x32_f16(a, b3, acc3, 0, 0, 0);
        }
        const int cbase = n0 + lr;
#pragma unroll
        for (int r = 0; r < 4; r++) {
            const int node = rbase + r;
            if (node < N_NODES) {
                __half* p = xh1 + (size_t)node * (HEADS * HID) + cbase;
                p[0]  = __float2half(acc0[r]);
                p[16] = __float2half(acc1[r]);
                p[32] = __float2half(acc2[r]);
                p[48] = __float2half(acc3[r]);
            }
        }
        const int h = nb;
        const float a0 = as1[(h << 6) + lr +  0], a1 = as1[(h << 6) + lr + 16];
        const float a2 = as1[(h << 6) + lr + 32], a3 = as1[(h << 6) + lr + 48];
        const float d0 = ad1[(h << 6) + lr +  0], d1 = ad1[(h << 6) + lr + 16];
        const float d2 = ad1[(h << 6) + lr + 32], d3 = ad1[(h << 6) + lr + 48];
#pragma unroll
        for (int r = 0; r < 4; r++) {
            float ps = acc0[r] * a0 + acc1[r] * a1 + acc2[r] * a2 + acc3[r] * a3;
            float pd = acc0[r] * d0 + acc1[r] * d1 + acc2[r] * d2 + acc3[r] * d3;
            ps += __shfl_xor(ps, 1); pd += __shfl_xor(pd, 1);
            ps += __shfl_xor(ps, 2); pd += __shfl_xor(pd, 2);
            ps += __shfl_xor(ps, 4); pd += __shfl_xor(pd, 4);
            ps += __shfl_xor(ps, 8); pd += __shfl_xor(pd, 8);
            if (lr == 0) {
                const int node = rbase + r;
                if (node < N_NODES) {
                    als[node * HEADS + h] = ps;
                    ald[node * HEADS + h] = pd;
                }
            }
        }
    }
}

// ---------------- K3: layer-1 aggregation, wave/node, 8 gathers in flight ----------------
__global__ void k_agg1_h(const int* __restrict__ cnt, const int* __restrict__ esrc,
                         const float* __restrict__ als, const float* __restrict__ ald,
                         const __half* __restrict__ xh1, float* __restrict__ agg1) {
    const int d = blockIdx.x * 4 + (threadIdx.x >> 6);
    const int lane = threadIdx.x & 63;
    if (d >= N_NODES) return;
    const int hq = lane >> 4;
    const int he = lane & 3;
    const float adh = ald[d * 4 + he];
    const int base = d << 6;
    const int total = cnt[d] + 1;   // + self loop
    float acc0 = 0.f, acc1 = 0.f, acc2 = 0.f, acc3 = 0.f;
    float denp = 0.f;
    const size_t lby = (size_t)(lane << 3);
    for (int t0 = 0; t0 < total; t0 += 16) {
        int m = total - t0; if (m > 16) m = 16;
        const int slot = lane >> 2;
        float ev = 0.f; int s = d;
        if (slot < m) {
            const int t = t0 + slot;
            if (t > 0) s = esrc[base + t - 1];
            ev = expf(lrelu(als[s * 4 + he] + adh));
        }
        denp += ev;
        int j = 0;
        for (; j + 8 <= m; j += 8) {
            int ss[8]; float cc[8]; float2 rr[8];
#pragma unroll
            for (int u = 0; u < 8; u++) ss[u] = __shfl(s, (j + u) * 4);
#pragma unroll
            for (int u = 0; u < 8; u++)
                rr[u] = *(const float2*)((const char*)xh1 + ((size_t)ss[u] << 9) + lby);
#pragma unroll
            for (int u = 0; u < 8; u++) cc[u] = __shfl(ev, (j + u) * 4 + hq);
#pragma unroll
            for (int u = 0; u < 8; u++) {
                const float2 a = __half22float2(*(const __half2*)&rr[u].x);
                const float2 b = __half22float2(*(const __half2*)&rr[u].y);
                acc0 += cc[u] * a.x; acc1 += cc[u] * a.y;
                acc2 += cc[u] * b.x; acc3 += cc[u] * b.y;
            }
        }
        for (; j + 4 <= m; j += 4) {
            int ss[4]; float cc[4]; float2 rr[4];
#pragma unroll
            for (int u = 0; u < 4; u++) ss[u] = __shfl(s, (j + u) * 4);
#pragma unroll
            for (int u = 0; u < 4; u++)
                rr[u] = *(const float2*)((const char*)xh1 + ((size_t)ss[u] << 9) + lby);
#pragma unroll
            for (int u = 0; u < 4; u++) cc[u] = __shfl(ev, (j + u) * 4 + hq);
#pragma unroll
            for (int u = 0; u < 4; u++) {
                const float2 a = __half22float2(*(const __half2*)&rr[u].x);
                const float2 b = __half22float2(*(const __half2*)&rr[u].y);
                acc0 += cc[u] * a.x; acc1 += cc[u] * a.y;
                acc2 += cc[u] * b.x; acc3 += cc[u] * b.y;
            }
        }
        for (; j < m; j++) {
            const float cf = __shfl(ev, j * 4 + hq);
            const int sj   = __shfl(s, j * 4);
            const float2 raw = *(const float2*)((const char*)xh1 + ((size_t)sj << 9) + lby);
            const float2 a = __half22float2(*(const __half2*)&raw.x);
            const float2 b = __half22float2(*(const __half2*)&raw.y);
            acc0 += cf * a.x; acc1 += cf * a.y; acc2 += cf * b.x; acc3 += cf * b.y;
        }
    }
    denp += __shfl_xor(denp, 4);
    denp += __shfl_xor(denp, 8);
    denp += __shfl_xor(denp, 16);
    denp += __shfl_xor(denp, 32);
    const float deninv = 1.f / __shfl(denp, hq);
    acc0 *= deninv; acc1 *= deninv; acc2 *= deninv; acc3 *= deninv;
    acc0 += __shfl_xor(acc0, 16); acc0 += __shfl_xor(acc0, 32);
    acc1 += __shfl_xor(acc1, 16); acc1 += __shfl_xor(acc1, 32);
    acc2 += __shfl_xor(acc2, 16); acc2 += __shfl_xor(acc2, 32);
    acc3 += __shfl_xor(acc3, 16); acc3 += __shfl_xor(acc3, 32);
    if (lane < 16) {
        float4 st = { 0.25f * acc0, 0.25f * acc1, 0.25f * acc2, 0.25f * acc3 };
        *(float4*)(agg1 + (size_t)d * HID + lane * 4) = st;
    }
}

// ---------------- K5: xh2h = half(relu(agg1+b1) @ W2) via MFMA + fused als2/ald2 ----------------
__global__ void k_gemm2_mfma(const float* __restrict__ agg1, const float* __restrict__ b1,
                             const __half* __restrict__ w2t, const float* __restrict__ as2,
                             const float* __restrict__ ad2, __half* __restrict__ xh2,
                             float* __restrict__ als, float* __restrict__ ald) {
    __shared__ _Float16 ash[64][72];
    __shared__ _Float16 wsh[128][72];
    const int tid = threadIdx.x;
    const int m0 = blockIdx.x * 64;
#pragma unroll
    for (int i = 0; i < 4; i++) {
        const int f = tid + i * 256;
        const int r = f >> 4;
        const int k4 = (f & 15) * 4;
        const int gr = (m0 + r < N_NODES) ? (m0 + r) : (N_NODES - 1);
        float4 v = *(const float4*)(agg1 + (size_t)gr * HID + k4);
        v.x += b1[k4 + 0]; v.y += b1[k4 + 1];
        v.z += b1[k4 + 2]; v.w += b1[k4 + 3];
        v.x = v.x > 0.f ? v.x : 0.f;
        v.y = v.y > 0.f ? v.y : 0.f;
        v.z = v.z > 0.f ? v.z : 0.f;
        v.w = v.w > 0.f ? v.w : 0.f;
        half4v hv = { (_Float16)v.x, (_Float16)v.y, (_Float16)v.z, (_Float16)v.w };
        *(half4v*)&ash[r][k4] = hv;
    }
#pragma unroll
    for (int i = 0; i < 4; i++) {
        const int u = tid + i * 256;
        const int r = u >> 3;
        const int k = (u & 7) * 8;
        *(half8v*)&wsh[r][k] = *(const half8v*)(w2t + (size_t)r * HID + k);
    }
    __syncthreads();
    const int w = tid >> 6, l = tid & 63;
    const int lr = l & 15, lk = (l >> 4) * 8;
    float4v acc[8];
#pragma unroll
    for (int c = 0; c < 8; c++) acc[c] = (float4v){0.f, 0.f, 0.f, 0.f};
#pragma unroll
    for (int k0 = 0; k0 < HID; k0 += 32) {
        const half8v a = *(const half8v*)&ash[w * 16 + lr][k0 + lk];
#pragma unroll
        for (int c = 0; c < 8; c++) {
            const half8v b = *(const half8v*)&wsh[c * 16 + lr][k0 + lk];
            acc[c] = __builtin_amdgcn_mfma_f32_16x16x32_f16(a, b, acc[c], 0, 0, 0);
        }
    }
    const int rbase = m0 + w * 16 + (l >> 4) * 4;
#pragma unroll
    for (int r = 0; r < 4; r++) {
        const int node = rbase + r;
        if (node < N_NODES) {
            __half* p = xh2 + (size_t)node * (HEADS * HID2) + lr;
#pragma unroll
            for (int c = 0; c < 8; c++) p[c * 16] = __float2half(acc[c][r]);
        }
    }
    float av[8], dv[8];
#pragma unroll
    for (int c = 0; c < 8; c++) {
        const int hh = c >> 1, cih = lr + 16 * (c & 1);
        av[c] = as2[hh * HID2 + cih];
        dv[c] = ad2[hh * HID2 + cih];
    }
#pragma unroll
    for (int r = 0; r < 4; r++) {
        float ps0 = acc[0][r] * av[0] + acc[1][r] * av[1];
        float ps1 = acc[2][r] * av[2] + acc[3][r] * av[3];
        float ps2 = acc[4][r] * av[4] + acc[5][r] * av[5];
        float ps3 = acc[6][r] * av[6] + acc[7][r] * av[7];
        float pd0 = acc[0][r] * dv[0] + acc[1][r] * dv[1];
        float pd1 = acc[2][r] * dv[2] + acc[3][r] * dv[3];
        float pd2 = acc[4][r] * dv[4] + acc[5][r] * dv[5];
        float pd3 = acc[6][r] * dv[6] + acc[7][r] * dv[7];
#pragma unroll
        for (int off = 1; off <= 8; off <<= 1) {
            ps0 += __shfl_xor(ps0, off); ps1 += __shfl_xor(ps1, off);
            ps2 += __shfl_xor(ps2, off); ps3 += __shfl_xor(ps3, off);
            pd0 += __shfl_xor(pd0, off); pd1 += __shfl_xor(pd1, off);
            pd2 += __shfl_xor(pd2, off); pd3 += __shfl_xor(pd3, off);
        }
        if (lr == 0) {
            const int node = rbase + r;
            if (node < N_NODES) {
                float4 sv = { ps0, ps1, ps2, ps3 };
                float4 dvv = { pd0, pd1, pd2, pd3 };
                *(float4*)(als + (size_t)node * HEADS) = sv;
                *(float4*)(ald + (size_t)node * HEADS) = dvv;
            }
        }
    }
}

// ---------------- K7: layer-2 aggregation + fused final projections ----------------
__global__ void k_agg2_final(const int* __restrict__ cnt, const int* __restrict__ esrc,
                             const float* __restrict__ als, const float* __restrict__ ald,
                             const __half* __restrict__ xh2, const float* __restrict__ b2,
                             const float* __restrict__ Wmu, const float* __restrict__ bmu,
                             const float* __restrict__ Wlv, const float* __restrict__ blv,
                             float* __restrict__ out) {
    const int d = blockIdx.x * 4 + (threadIdx.x >> 6);
    const int lane = threadIdx.x & 63;
    if (d >= N_NODES) return;
    const int hq = lane >> 4;
    const int he = lane & 3;
    const float adh = ald[d * 4 + he];
    const int base = d << 6;
    const int total = cnt[d] + 1;   // + self loop
    float acc0 = 0.f, acc1 = 0.f;
    float denp = 0.f;
    const size_t lby = (size_t)(lane << 2);
    for (int t0 = 0; t0 < total; t0 += 16) {
        int m = total - t0; if (m > 16) m = 16;
        const int slot = lane >> 2;
        float ev = 0.f; int s = d;
        if (slot < m) {
            const int t = t0 + slot;
            if (t > 0) s = esrc[base + t - 1];
            ev = expf(lrelu(als[s * 4 + he] + adh));
        }
        denp += ev;
        int j = 0;
        for (; j + 8 <= m; j += 8) {
            int ss[8]; float cc[8]; __half2 rr[8];
#pragma unroll
            for (int u = 0; u < 8; u++) ss[u] = __shfl(s, (j + u) * 4);
#pragma unroll
            for (int u = 0; u < 8; u++)
                rr[u] = *(const __half2*)((const char*)xh2 + ((size_t)ss[u] << 8) + lby);
#pragma unroll
            for (int u = 0; u < 8; u++) cc[u] = __shfl(ev, (j + u) * 4 + hq);
#pragma unroll
            for (int u = 0; u < 8; u++) {
                const float2 xv = __half22float2(rr[u]);
                acc0 += cc[u] * xv.x; acc1 += cc[u] * xv.y;
            }
        }
        for (; j + 4 <= m; j += 4) {
            int ss[4]; float cc[4]; __half2 rr[4];
#pragma unroll
            for (int u = 0; u < 4; u++) ss[u] = __shfl(s, (j + u) * 4);
#pragma unroll
            for (int u = 0; u < 4; u++)
                rr[u] = *(const __half2*)((const char*)xh2 + ((size_t)ss[u] << 8) + lby);
#pragma unroll
            for (int u = 0; u < 4; u++) cc[u] = __shfl(ev, (j + u) * 4 + hq);
#pragma unroll
            for (int u = 0; u < 4; u++) {
                const float2 xv = __half22float2(rr[u]);
                acc0 += cc[u] * xv.x; acc1 += cc[u] * xv.y;
            }
        }
        for (; j < m; j++) {
            const float cf = __shfl(ev, j * 4 + hq);
            const int sj   = __shfl(s, j * 4);
            const __half2 hv = *(const __half2*)((const char*)xh2 + ((size_t)sj << 8) + lby);
            const float2 xv = __half22float2(hv);
            acc0 += cf * xv.x; acc1 += cf * xv.y;
        }
    }
    denp += __shfl_xor(denp, 4);
    denp += __shfl_xor(denp, 8);
    denp += __shfl_xor(denp, 16);
    denp += __shfl_xor(denp, 32);
    const float deninv = 1.f / __shfl(denp, hq);
    acc0 *= deninv; acc1 *= deninv;
    acc0 += __shfl_xor(acc0, 16); acc0 += __shfl_xor(acc0, 32);
    acc1 += __shfl_xor(acc1, 16); acc1 += __shfl_xor(acc1, 32);
    const int cp = lane & 15;
    float h0 = 0.25f * acc0 + b2[2 * cp];
    float h1 = 0.25f * acc1 + b2[2 * cp + 1];
    h0 = h0 > 0.f ? h0 : 0.f;
    h1 = h1 > 0.f ? h1 : 0.f;
    const int jj = lane & 31;
    const bool lv = lane >= 32;
    const float* Wp = lv ? Wlv : Wmu;
    const float* bp = lv ? blv : bmu;
    float o = bp[jj];
#pragma unroll
    for (int k = 0; k < 16; k++) {
        const float e0 = __shfl(h0, k);
        const float e1 = __shfl(h1, k);
        o += e0 * Wp[(2 * k) * LATENT + jj] + e1 * Wp[(2 * k + 1) * LATENT + jj];
    }
    out[(lv ? (size_t)N_NODES * LATENT : (size_t)0) + (size_t)d * LATENT + jj] = o;
}

extern "C" void kernel_launch(void* const* d_in, const int* in_sizes, int n_in,
                              void* d_out, int out_size, void* d_ws, size_t ws_size,
                              hipStream_t stream) {
    const float* x    = (const float*)d_in[0];
    const int*   ei   = (const int*)d_in[1];
    const float* W1   = (const float*)d_in[2];
    const float* as1  = (const float*)d_in[3];
    const float* ad1  = (const float*)d_in[4];
    const float* b1   = (const float*)d_in[5];
    const float* W2   = (const float*)d_in[6];
    const float* as2  = (const float*)d_in[7];
    const float* ad2  = (const float*)d_in[8];
    const float* b2   = (const float*)d_in[9];
    const float* Wmu  = (const float*)d_in[10];
    const float* bmu  = (const float*)d_in[11];
    const float* Wlv  = (const float*)d_in[12];
    const float* blv  = (const float*)d_in[13];
    float* out = (float*)d_out;
    float* ws  = (float*)d_ws;

    __half* xh1h = (__half*)(ws + OFF_XH1H);
    __half* xh2h = (__half*)(ws + OFF_XH2H);
    __half* w1th = (__half*)(ws + OFF_W1TH);
    __half* w2th = (__half*)(ws + OFF_W2TH);
    float* als1 = ws + OFF_ALS1;
    float* ald1 = ws + OFF_ALD1;
    float* agg1 = ws + OFF_AGG1;
    float* als2 = ws + OFF_ALS2;
    float* ald2 = ws + OFF_ALD2;
    int* cur  = (int*)(ws + OFF_CUR);
    int* esrc = (int*)(ws + OFF_ESRC);

    k_prep<<<160 + NB_ZERO, 256, 0, stream>>>(W1, W2, w1th, w2th, cur);

    // hybrid dispatch: GEMM1 blocks + edge-binning blocks co-scheduled
    k_gemm1_mfma<<<GB1 + NBIN, 256, 0, stream>>>(x, w1th, as1, ad1, xh1h,
                                                 als1, ald1, ei, cur, esrc);

    k_agg1_h<<<(N_NODES + 3) / 4, 256, 0, stream>>>(cur, esrc, als1, ald1, xh1h, agg1);

    k_gemm2_mfma<<<(N_NODES + 63) / 64, 256, 0, stream>>>(agg1, b1, w2th, as2, ad2,
                                                          xh2h, als2, ald2);

    k_agg2_final<<<(N_NODES + 3) / 4, 256, 0, stream>>>(cur, esrc, als2, ald2, xh2h,
                                                        b2, Wmu, bmu, Wlv, blv, out);
}